// Round 5
// baseline (194.862 us; speedup 1.0000x reference)
//
#include <hip/hip_runtime.h>
#include <cstdint>
#include <cstddef>

#define B_ 16
#define Q_ 4096
#define G_ 128
#define C_ 80
#define QCHUNK 16
#define QBLK 64                 // q's per A-block (4 chunks)
#define CHPB (QBLK / QCHUNK)    // 4 chunks per block
#define NCH (Q_ / QBLK)         // 64 partial lists per column

typedef unsigned long long u64;
#define U64MAX 0xffffffffffffffffull

// pack (cost,q) into a sortable u64 key: asc key order == lex (cost asc, q asc)
__device__ __forceinline__ u64 packkey(float v, int q) {
    unsigned int bts = __float_as_uint(v);
    if (bts == 0x80000000u) bts = 0u;  // -0.0 -> +0.0
    bts = (bts & 0x80000000u) ? ~bts : (bts | 0x80000000u);
    return ((u64)bts << 32) | (unsigned int)q;
}

__device__ __forceinline__ u64 umin64(u64 a, u64 b) { return a < b ? a : b; }
__device__ __forceinline__ u64 umax64(u64 a, u64 b) { return a > b ? a : b; }

// merge two desc-sorted 5-lists -> top-5 desc (branchless network)
__device__ __forceinline__ void merge5_desc(
    float& a0, float& a1, float& a2, float& a3, float& a4,
    float b0, float b1, float b2, float b3, float b4)
{
    const float r0 = fmaxf(a0, b0);
    const float r1 = fmaxf(fmaxf(a1, b1), fminf(a0, b0));
    const float r2 = fmaxf(fmaxf(a2, b2), fmaxf(fminf(a0, b1), fminf(a1, b0)));
    const float r3 = fmaxf(fmaxf(a3, b3),
                     fmaxf(fminf(a0, b2), fmaxf(fminf(a1, b1), fminf(a2, b0))));
    const float r4 = fmaxf(fmaxf(a4, b4),
                     fmaxf(fmaxf(fminf(a0, b3), fminf(a3, b0)),
                           fmaxf(fminf(a1, b2), fminf(a2, b1))));
    a0 = r0; a1 = r1; a2 = r2; a3 = r3; a4 = r4;
}

// merge two asc-sorted 5-lists of u64 keys -> bottom-5 asc
__device__ __forceinline__ void merge5_asc(
    u64& a0, u64& a1, u64& a2, u64& a3, u64& a4,
    u64 b0, u64 b1, u64 b2, u64 b3, u64 b4)
{
    const u64 r0 = umin64(a0, b0);
    const u64 r1 = umin64(umin64(a1, b1), umax64(a0, b0));
    const u64 r2 = umin64(umin64(a2, b2), umin64(umax64(a0, b1), umax64(a1, b0)));
    const u64 r3 = umin64(umin64(a3, b3),
                   umin64(umax64(a0, b2), umin64(umax64(a1, b1), umax64(a2, b0))));
    const u64 r4 = umin64(umin64(a4, b4),
                   umin64(umin64(umax64(a0, b3), umax64(a3, b0)),
                          umin64(umax64(a1, b2), umax64(a2, b1))));
    a0 = r0; a1 = r1; a2 = r2; a3 = r3; a4 = r4;
}

__device__ __forceinline__ float focal_cost(float x) {
    float p;
    if (x >= 0.f) { const float e = expf(-x); p = 1.f / (1.f + e); }
    else          { const float e = expf(x);  p = e / (1.f + e); }
    const float pos = 0.25f * (1.f - p) * (1.f - p) * (-logf(p + 1e-8f));
    const float neg = 0.75f * p * p * (-logf(1.f - p + 1e-8f));
    return pos - neg;
}

// stable conditional-swap insertion level for (cost,q) lex order (strict <)
__device__ __forceinline__ void ins_level(float& c, int& j, float& x, int& qx) {
    const bool s  = x < c;
    const float nc = s ? x : c;
    const float nx = s ? c : x;
    const int   nj = s ? qx : j;
    const int   nq = s ? j : qx;
    c = nc; x = nx; j = nj; qx = nq;
}

// ---------------------------------------------------------------------------
// Kernel A: fused cost/iou + focal.  QBLK=64 (4 chunks, best measured
// amortization) but with 512 THREADS: grid 1024 = 4 blocks/CU x 8 waves =
// 32 waves/CU occupancy cap (round-3 QBLK=64 was grid-limited at 16/32,
// measured Occ 30%; round-4 QBLK=32 raised Occ but doubled preamble+writes,
// A got slower).  Thread map: g = tid&127, qq = tid>>7 (4 q-lanes).
// Partial lists back to 64/col (-8MB writes vs round 4).  Also zeroes cnt.
// ---------------------------------------------------------------------------
__global__ __launch_bounds__(512) void fused_cost_kernel(
    const float* __restrict__ logits,
    const float* __restrict__ pboxes,
    const float* __restrict__ gboxes,
    const int*   __restrict__ glabels,
    float* __restrict__ out_cost,
    float* __restrict__ out_iou,
    float* __restrict__ piou,
    u64*   __restrict__ pcost,
    int*   __restrict__ ramin,
    int*   __restrict__ cnt)
{
    const int tid = threadIdx.x;
    const int g   = tid & 127;
    const int qq  = tid >> 7;            // 0..3
    const int ci  = blockIdx.x, b = blockIdx.y;

    __shared__ float pq[QCHUNK][16];
    __shared__ int   fgf[QCHUNK];
    __shared__ float lbuf[QCHUNK * 80];          // focal class-cost table
    __shared__ float s_cost[QCHUNK][G_ + 1];     // cost tile (b32, padded)
    __shared__ float s_iou[QCHUNK][G_ + 1];      // iou tile

    // zero cnt for this block's 64 q's (consumed by B's atomics)
    if (tid < QBLK) cnt[b * Q_ + ci * QBLK + tid] = 0;

    // ---- per-thread gt constants (loaded once for all 4 chunks) ----
    const float4* gb4 = (const float4*)(gboxes + ((size_t)b * G_ + g) * 8);
    const float4 gA = gb4[0], gB = gb4[1];
    const float g0 = gA.x, g1 = gA.y, g2 = gA.z, g3 = gA.w;
    const float g4 = gB.x, g5 = gB.y, g6 = gB.z, g7 = gB.w;
    const float gxc = (g0 + g2 + g4 + g6) * 0.25f;
    const float gyc = (g1 + g3 + g5 + g7) * 0.25f;
    const float gw = sqrtf((g0 - g2) * (g0 - g2) + (g1 - g3) * (g1 - g3));
    const float gh = sqrtf((g2 - g4) * (g2 - g4) + (g3 - g5) * (g3 - g5));
    const float gax0 = gxc - gw * 0.5f, gay0 = gyc - gh * 0.5f;
    const float gax1 = gxc + gw * 0.5f, gay1 = gyc + gh * 0.5f;
    const float garea = (gax1 - gax0) * (gay1 - gay0);
    const float v1x = g2 - g0, v1y = g3 - g1, v2x = g4 - g0, v2y = g5 - g1;
    const float gt_area = fabsf(v1x * v2y - v1y * v2x) * 0.5f;
    const float mxx = fmaxf(fmaxf(g0, g2), fmaxf(g4, g6));
    const float mnx = fminf(fminf(g0, g2), fminf(g4, g6));
    const float mxy = fmaxf(fmaxf(g1, g3), fmaxf(g5, g7));
    const float mny = fminf(fminf(g1, g3), fminf(g5, g7));
    const float dgx = mxx - mnx, dgy = mxy - mny;
    const float radius = sqrtf(dgx * dgx + dgy * dgy) / 32.0f;
    const float thresh = gt_area / radius;
    const int lab = glabels[b * G_ + g];

    // running selection state (used by tid<128 threads only)
    float c0 = 1e38f, c1 = 1e38f, c2 = 1e38f, c3 = 1e38f, c4 = 1e38f;
    int   j0 = 0, j1 = 0, j2 = 0, j3 = 0, j4 = 0;
    float t0 = 0.f, t1 = 0.f, t2 = 0.f, t3 = 0.f, t4 = 0.f;

    for (int ch = 0; ch < CHPB; ++ch) {
        const int q0 = ci * QBLK + ch * QCHUNK;

        // ---- stage pred boxes (16 q x 8 floats = 32 float4) ----
        if (tid < 32) {
            const float4 v = ((const float4*)(pboxes + ((size_t)b * Q_ + q0) * 8))[tid];
            *(float4*)&pq[tid >> 1][(tid & 1) * 4] = v;
        }
        __syncthreads();
        if (tid < QCHUNK) {
            const float* pr = pq[tid];
            const float p0 = pr[0], p1 = pr[1], p2 = pr[2], p3 = pr[3];
            const float p4 = pr[4], p5v = pr[5], p6 = pr[6], p7 = pr[7];
            const float pxc = (p0 + p2 + p4 + p6) * 0.25f;
            const float pyc = (p1 + p3 + p5v + p7) * 0.25f;
            const float pw = sqrtf((p0 - p2) * (p0 - p2) + (p1 - p3) * (p1 - p3));
            const float ph = sqrtf((p2 - p4) * (p2 - p4) + (p3 - p5v) * (p3 - p5v));
            pq[tid][8]  = pxc;
            pq[tid][9]  = pyc;
            pq[tid][10] = pxc - pw * 0.5f;
            pq[tid][11] = pyc - ph * 0.5f;
            pq[tid][12] = pxc + pw * 0.5f;
            pq[tid][13] = pyc + ph * 0.5f;
            pq[tid][14] = pw * ph;
            fgf[tid] = 0;
        }
        __syncthreads();
        // focal class-cost table for this chunk (16 q x 80 classes)
        for (int j = tid; j < QCHUNK * 80; j += 512)
            lbuf[j] = focal_cost(logits[((size_t)b * Q_ + q0) * 80 + j]);

        // ---- fg mask (any over g); both g-half waves of a q-lane OR in ----
        const int lane0 = ((tid & 63) == 0);
        for (int i = 0; i < QCHUNK / 4; ++i) {
            const int ql = 4 * i + qq;
            const float dx = pq[ql][8] - gxc, dy = pq[ql][9] - gyc;
            const int in = sqrtf(dx * dx + dy * dy) <= thresh;
            const int anyin = __any(in);
            if (anyin && lane0) fgf[ql] = 1;
        }
        __syncthreads();

        // ---- main loop: 4 rows/thread; 32-bit incremental addressing ----
        int o = (b * Q_ + q0 + qq) * G_ + g;
        #pragma unroll
        for (int jj = 0; jj < 4; ++jj) {
            const int qls = 4 * jj + qq;       // 0..15
            const float4 prA = *(const float4*)&pq[qls][0];
            const float4 prB = *(const float4*)&pq[qls][4];
            const float4 prC = *(const float4*)&pq[qls][8];
            const float4 prD = *(const float4*)&pq[qls][12];
            const float p0 = prA.x, p1 = prA.y, p2 = prA.z, p3 = prA.w;
            const float p4 = prB.x, p5v = prB.y, p6 = prB.z, p7 = prB.w;
            const float pxc = prC.x, pyc = prC.y;
            const float pax0 = prC.z, pay0 = prC.w, pax1 = prD.x, pay1 = prD.y;
            const float parea = prD.z;

            const float l1 = fabsf(p0 - g0) + fabsf(p1 - g1) + fabsf(p2 - g2)
                           + fabsf(p3 - g3) + fabsf(p4 - g4) + fabsf(p5v - g5)
                           + fabsf(p6 - g6) + fabsf(p7 - g7);

            const float ltx = fmaxf(pax0, gax0), lty = fmaxf(pay0, gay0);
            const float rbx = fminf(pax1, gax1), rby = fminf(pay1, gay1);
            const float iw = fmaxf(rbx - ltx, 0.f), ih = fmaxf(rby - lty, 0.f);
            const float inter = iw * ih;
            const float iou = inter / (parea + garea - inter + 1e-8f);

            const float ew = fmaxf(pax1, gax1) - fminf(pax0, gax0);
            const float eh = fmaxf(pay1, gay1) - fminf(pay0, gay0);
            const float cc2 = ew * ew + eh * eh + 1e-8f;
            const float dx = pxc - gxc, dy = pyc - gyc;
            const float diou = iou - (dx * dx + dy * dy) / cc2;

            const float cclass = lbuf[qls * 80 + lab];
            const float cost = 5.f * l1 + 2.f * cclass + 2.f * diou
                             + (fgf[qls] ? 0.f : 10000.f);

            out_cost[o] = cost;
            out_iou[o]  = iou;
            o += 4 * G_;
            s_cost[qls][g] = cost;
            s_iou[qls][g]  = iou;
        }
        __syncthreads();   // tiles complete

        if (tid < G_) {
            // running per-column selection; insert GLOBAL q (ascending order
            // across chunks -> stable strict-< == exact lex tie-break)
            #pragma unroll
            for (int qx2 = 0; qx2 < QCHUNK; ++qx2) {
                float x = s_cost[qx2][tid]; int qx = q0 + qx2;
                ins_level(c0, j0, x, qx);
                ins_level(c1, j1, x, qx);
                ins_level(c2, j2, x, qx);
                ins_level(c3, j3, x, qx);
                ins_level(c4, j4, x, qx);
                float y = s_iou[qx2][tid], m;
                m = fmaxf(t0, y); y = fminf(t0, y); t0 = m;
                m = fmaxf(t1, y); y = fminf(t1, y); t1 = m;
                m = fmaxf(t2, y); y = fminf(t2, y); t2 = m;
                m = fmaxf(t3, y); y = fminf(t3, y); t3 = m;
                t4 = fmaxf(t4, y);
            }
        } else if (tid < 256) {
            // ---- row argmin (first-index tie-break), 8 lanes per q ----
            const int t    = tid - 128;
            const int part = t & 7;        // 0..7
            const int row  = t >> 3;       // 0..15
            float v = 1e38f; int mg = 0x7fffffff;
            #pragma unroll
            for (int j = 0; j < 16; ++j) {
                const int gg = part * 16 + j;          // ascending per lane
                const float c = s_cost[row][gg];
                if (c < v) { v = c; mg = gg; }         // strict <: first index
            }
            #pragma unroll
            for (int off = 1; off < 8; off <<= 1) {
                const float ov = __shfl_xor(v, off);
                const int   og = __shfl_xor(mg, off);
                if (ov < v || (ov == v && og < mg)) { v = ov; mg = og; }
            }
            if (part == 0) ramin[b * Q_ + q0 + row] = mg;
        }
        __syncthreads();   // tiles reusable next chunk
    }

    if (tid < G_) {
        // coalesced layout: [B][NCH][G][5]
        const size_t pbase = (((size_t)b * NCH + ci) * G_ + tid) * 5;
        piou[pbase + 0] = t0; piou[pbase + 1] = t1; piou[pbase + 2] = t2;
        piou[pbase + 3] = t3; piou[pbase + 4] = t4;
        pcost[pbase + 0] = packkey(c0, j0);
        pcost[pbase + 1] = packkey(c1, j1);
        pcost[pbase + 2] = packkey(c2, j2);
        pcost[pbase + 3] = packkey(c3, j3);
        pcost[pbase + 4] = packkey(c4, j4);
    }
}

// ---------------------------------------------------------------------------
// Kernel B: per-column, ONE WAVE (64 threads = one thread per chunk-list):
// butterfly-merge 64 sorted 5-lists -> cand, dyn_k, scatter cnt/gsel.
// 2048 blocks -> fully parallel.  Merge order identical to verified round-3.
// ---------------------------------------------------------------------------
__global__ __launch_bounds__(64) void dynk_scatter_kernel(
    const u64*   __restrict__ pcost,
    const float* __restrict__ piou,
    u64* __restrict__ cand,
    int* __restrict__ cnt,
    int* __restrict__ gsel)
{
    const int col = blockIdx.x;          // b*G + g
    const int b = col >> 7, g = col & 127;
    const int ln = threadIdx.x;          // = chunk index ci (0..63)

    // layout [B][NCH][G][5]
    const size_t base = (((size_t)b * NCH + ln) * G_ + g) * 5;

    u64 k0 = pcost[base + 0], k1 = pcost[base + 1], k2 = pcost[base + 2],
        k3 = pcost[base + 3], k4 = pcost[base + 4];
    float t0 = piou[base + 0], t1 = piou[base + 1], t2 = piou[base + 2],
          t3 = piou[base + 3], t4 = piou[base + 4];

    #pragma unroll
    for (int off = 1; off < 64; off <<= 1) {
        merge5_asc(k0, k1, k2, k3, k4,
                   __shfl_xor(k0, off), __shfl_xor(k1, off), __shfl_xor(k2, off),
                   __shfl_xor(k3, off), __shfl_xor(k4, off));
        merge5_desc(t0, t1, t2, t3, t4,
                    __shfl_xor(t0, off), __shfl_xor(t1, off), __shfl_xor(t2, off),
                    __shfl_xor(t3, off), __shfl_xor(t4, off));
    }

    if (ln == 0) {
        cand[(size_t)col * 5 + 0] = k0;
        cand[(size_t)col * 5 + 1] = k1;
        cand[(size_t)col * 5 + 2] = k2;
        cand[(size_t)col * 5 + 3] = k3;
        cand[(size_t)col * 5 + 4] = k4;

        const float s = t0 + t1 + t2 + t3 + t4;
        int dynk = (int)s;
        if (dynk < 1) dynk = 1;
        if (dynk > 5) dynk = 5;
        const u64 ks[5] = {k0, k1, k2, k3, k4};
        #pragma unroll
        for (int i = 0; i < 5; ++i) {
            if (i < dynk) {
                const int q = (int)(ks[i] & 0xffffffffu);
                atomicAdd(&cnt[b * Q_ + q], 1);
                gsel[b * Q_ + q] = g;   // only read when cnt==1
            }
        }
    }
}

// ---------------------------------------------------------------------------
// Kernel C: per-batch event-driven refinement loop (1024 threads) — the
// verified round-1 structure.
// ---------------------------------------------------------------------------
__global__ __launch_bounds__(1024) void loop_kernel(
    const float* __restrict__ cost,
    const int* __restrict__ cnt,
    const int* __restrict__ gsel,
    const int* __restrict__ ramin,
    const u64* __restrict__ cand,
    int* __restrict__ rmatch_final)
{
    const int b = blockIdx.x, tid = threadIdx.x;
    const int wv = tid >> 6, ln = tid & 63;

    __shared__ short rmatch[Q_];            // 8 KB
    __shared__ unsigned char s_ra[Q_];      // 4 KB
    __shared__ int newh[Q_];                // 16 KB
    __shared__ unsigned char newg[Q_];      // 4 KB
    __shared__ u64 scand[G_][5];            // 5 KB
    __shared__ int ptrs[G_], col_cnt[G_], unm_list[G_], prop[G_], fb_slot[G_], touched[G_];
    __shared__ int n_unm, n_fb, n_touch;

    for (int q = tid; q < Q_; q += 1024) {
        const int c  = cnt[b * Q_ + q];
        const int ra = ramin[b * Q_ + q];
        s_ra[q] = (unsigned char)ra;
        newh[q] = 0;
        rmatch[q] = (c == 0) ? (short)-1
                             : (c == 1 ? (short)gsel[b * Q_ + q] : (short)ra);
    }
    if (tid < G_) { col_cnt[tid] = 0; ptrs[tid] = 0; }
    if (tid < G_ * 5)
        scand[tid / 5][tid % 5] = cand[(size_t)b * G_ * 5 + tid];
    __syncthreads();
    for (int q = tid; q < Q_; q += 1024)
        if (rmatch[q] >= 0) atomicAdd(&col_cnt[rmatch[q]], 1);
    __syncthreads();

    const float* costb = cost + (size_t)b * Q_ * G_;

    for (int it = 0; it < G_; ++it) {
        if (tid == 0) { n_unm = 0; n_fb = 0; n_touch = 0; }
        __syncthreads();
        if (tid < G_ && col_cnt[tid] == 0)
            unm_list[atomicAdd(&n_unm, 1)] = tid;
        __syncthreads();
        const int nu = n_unm;
        if (nu == 0) break;

        // propose: first unmatched candidate, else mark for fallback scan
        if (tid < nu) {
            const int g = unm_list[tid];
            int p = ptrs[g];
            int q = -1;
            while (p < 5) {
                const int cq = (int)(scand[g][p] & 0xffffffffu);
                if (rmatch[cq] < 0) { q = cq; break; }
                ++p;
            }
            ptrs[g] = p;
            prop[tid] = q;
            if (q < 0) fb_slot[atomicAdd(&n_fb, 1)] = tid;
        }
        __syncthreads();

        // wave-parallel fallback (16 waves): bottom-5 unmatched + refill.
        const int nf = n_fb;
        for (int i = wv; i < nf; i += 16) {
            const int slot = fb_slot[i];
            const int g = unm_list[slot];
            const float* colp = costb + g;
            u64 k0 = U64MAX, k1 = U64MAX, k2 = U64MAX, k3 = U64MAX, k4 = U64MAX;
            for (int q = ln; q < Q_; q += 64) {
                if (rmatch[q] < 0) {
                    const float v = colp[(size_t)q * G_];
                    const u64 kk = packkey(v, q);
                    if (kk < k4) {
                        if (kk < k0)      { k4 = k3; k3 = k2; k2 = k1; k1 = k0; k0 = kk; }
                        else if (kk < k1) { k4 = k3; k3 = k2; k2 = k1; k1 = kk; }
                        else if (kk < k2) { k4 = k3; k3 = k2; k2 = kk; }
                        else if (kk < k3) { k4 = k3; k3 = kk; }
                        else              { k4 = kk; }
                    }
                }
            }
            #pragma unroll
            for (int off = 1; off < 64; off <<= 1) {
                merge5_asc(k0, k1, k2, k3, k4,
                           __shfl_xor(k0, off), __shfl_xor(k1, off), __shfl_xor(k2, off),
                           __shfl_xor(k3, off), __shfl_xor(k4, off));
            }
            if (ln == 0) {
                scand[g][0] = k0; scand[g][1] = k1; scand[g][2] = k2;
                scand[g][3] = k3; scand[g][4] = k4;
                ptrs[g] = 0;
                prop[slot] = (int)(k0 & 0xffffffffu);
            }
        }
        __syncthreads();

        // hits
        if (tid < nu) {
            const int q = prop[tid];
            newg[q] = (unsigned char)unm_list[tid];  // consumed only when nh==1
            if (atomicAdd(&newh[q], 1) == 0)
                touched[atomicAdd(&n_touch, 1)] = q;
        }
        __syncthreads();

        // resolve (dedup): hits only land on unmatched rows
        const int nt = n_touch;
        if (tid < nt) {
            const int q = touched[tid];
            const int nh = newh[q];
            const int gg = (nh == 1) ? (int)newg[q] : (int)s_ra[q];
            rmatch[q] = (short)gg;
            atomicAdd(&col_cnt[gg], 1);
            newh[q] = 0;
        }
        __syncthreads();
    }

    for (int q = tid; q < Q_; q += 1024)
        rmatch_final[b * Q_ + q] = rmatch[q];
}

// ---------------------------------------------------------------------------
// Kernel D: expand rmatch -> full match plane (fully parallel float4 writes).
// ---------------------------------------------------------------------------
__global__ __launch_bounds__(256) void expand_kernel(
    const int* __restrict__ rmatch_final, float* __restrict__ out_match)
{
    const int idx = blockIdx.x * 256 + threadIdx.x;  // float4 index
    const int row = idx >> 5;                        // G/4 = 32 float4 per row
    const int gb  = (idx & 31) << 2;
    const int rm  = rmatch_final[row];
    float4 o;
    o.x = (rm == gb)     ? 1.f : 0.f;
    o.y = (rm == gb + 1) ? 1.f : 0.f;
    o.z = (rm == gb + 2) ? 1.f : 0.f;
    o.w = (rm == gb + 3) ? 1.f : 0.f;
    ((float4*)out_match)[idx] = o;
}

extern "C" void kernel_launch(void* const* d_in, const int* in_sizes, int n_in,
                              void* d_out, int out_size, void* d_ws, size_t ws_size,
                              hipStream_t stream) {
    const float* logits  = (const float*)d_in[0];
    const float* pboxes  = (const float*)d_in[1];
    const float* gboxes  = (const float*)d_in[2];
    const int*   glabels = (const int*)d_in[3];

    float* out = (float*)d_out;
    const size_t BQG = (size_t)B_ * Q_ * G_;
    float* out_match = out;
    float* out_cost  = out + BQG;
    float* out_iou   = out + 2 * BQG;

    // workspace layout (~9 MB)
    char* ws = (char*)d_ws;
    size_t off = 0;
    u64*   pcost  = (u64*)  (ws + off); off += (size_t)B_ * NCH * G_ * 5 * 8;
    float* piou   = (float*)(ws + off); off += (size_t)B_ * NCH * G_ * 5 * 4;
    u64*   cand   = (u64*)  (ws + off); off += (size_t)B_ * G_ * 5 * 8;
    int*   ramin  = (int*)  (ws + off); off += (size_t)B_ * Q_ * 4;
    int*   cnt    = (int*)  (ws + off); off += (size_t)B_ * Q_ * 4;
    int*   gsel   = (int*)  (ws + off); off += (size_t)B_ * Q_ * 4;
    int*   rmf    = (int*)  (ws + off); off += (size_t)B_ * Q_ * 4;

    fused_cost_kernel<<<dim3(NCH, B_), 512, 0, stream>>>(
        logits, pboxes, gboxes, glabels, out_cost, out_iou, piou, pcost, ramin, cnt);
    dynk_scatter_kernel<<<B_ * G_, 64, 0, stream>>>(pcost, piou, cand, cnt, gsel);
    loop_kernel<<<B_, 1024, 0, stream>>>(out_cost, cnt, gsel, ramin, cand, rmf);
    expand_kernel<<<(int)(BQG / 4 / 256), 256, 0, stream>>>(rmf, out_match);
}

// Round 6
// 184.924 us; speedup vs baseline: 1.0537x; 1.0537x over previous
//
#include <hip/hip_runtime.h>
#include <cstdint>
#include <cstddef>

#define B_ 16
#define Q_ 4096
#define G_ 128
#define C_ 80
#define QCHUNK 16
#define QBLK 64                 // q's per A-block (4 chunks)
#define CHPB (QBLK / QCHUNK)    // 4 chunks per block
#define NCH (Q_ / QBLK)         // 64 partial lists per column

typedef unsigned long long u64;
#define U64MAX 0xffffffffffffffffull

// pack (cost,q) into a sortable u64 key: asc key order == lex (cost asc, q asc)
__device__ __forceinline__ u64 packkey(float v, int q) {
    unsigned int bts = __float_as_uint(v);
    if (bts == 0x80000000u) bts = 0u;  // -0.0 -> +0.0
    bts = (bts & 0x80000000u) ? ~bts : (bts | 0x80000000u);
    return ((u64)bts << 32) | (unsigned int)q;
}

__device__ __forceinline__ u64 umin64(u64 a, u64 b) { return a < b ? a : b; }
__device__ __forceinline__ u64 umax64(u64 a, u64 b) { return a > b ? a : b; }

// merge two desc-sorted 5-lists -> top-5 desc (branchless network)
__device__ __forceinline__ void merge5_desc(
    float& a0, float& a1, float& a2, float& a3, float& a4,
    float b0, float b1, float b2, float b3, float b4)
{
    const float r0 = fmaxf(a0, b0);
    const float r1 = fmaxf(fmaxf(a1, b1), fminf(a0, b0));
    const float r2 = fmaxf(fmaxf(a2, b2), fmaxf(fminf(a0, b1), fminf(a1, b0)));
    const float r3 = fmaxf(fmaxf(a3, b3),
                     fmaxf(fminf(a0, b2), fmaxf(fminf(a1, b1), fminf(a2, b0))));
    const float r4 = fmaxf(fmaxf(a4, b4),
                     fmaxf(fmaxf(fminf(a0, b3), fminf(a3, b0)),
                           fmaxf(fminf(a1, b2), fminf(a2, b1))));
    a0 = r0; a1 = r1; a2 = r2; a3 = r3; a4 = r4;
}

// merge two asc-sorted 5-lists of u64 keys -> bottom-5 asc
__device__ __forceinline__ void merge5_asc(
    u64& a0, u64& a1, u64& a2, u64& a3, u64& a4,
    u64 b0, u64 b1, u64 b2, u64 b3, u64 b4)
{
    const u64 r0 = umin64(a0, b0);
    const u64 r1 = umin64(umin64(a1, b1), umax64(a0, b0));
    const u64 r2 = umin64(umin64(a2, b2), umin64(umax64(a0, b1), umax64(a1, b0)));
    const u64 r3 = umin64(umin64(a3, b3),
                   umin64(umax64(a0, b2), umin64(umax64(a1, b1), umax64(a2, b0))));
    const u64 r4 = umin64(umin64(a4, b4),
                   umin64(umin64(umax64(a0, b3), umax64(a3, b0)),
                          umin64(umax64(a1, b2), umax64(a2, b1))));
    a0 = r0; a1 = r1; a2 = r2; a3 = r3; a4 = r4;
}

__device__ __forceinline__ float focal_cost(float x) {
    float p;
    if (x >= 0.f) { const float e = expf(-x); p = 1.f / (1.f + e); }
    else          { const float e = expf(x);  p = e / (1.f + e); }
    const float pos = 0.25f * (1.f - p) * (1.f - p) * (-logf(p + 1e-8f));
    const float neg = 0.75f * p * p * (-logf(1.f - p + 1e-8f));
    return pos - neg;
}

// stable conditional-swap insertion level for (cost,q) lex order (strict <)
__device__ __forceinline__ void ins_level(float& c, int& j, float& x, int& qx) {
    const bool s  = x < c;
    const float nc = s ? x : c;
    const float nx = s ? c : x;
    const int   nj = s ? qx : j;
    const int   nq = s ? j : qx;
    c = nc; x = nx; j = nj; qx = nq;
}

// ---------------------------------------------------------------------------
// Kernel A: round-3 config VERBATIM (measured 64.5 us, the best of the three
// measured shapes: VALU-issue time is constant ~41 us across configs and this
// shape has the highest issue density -- 8 rows/thread ILP in the pair loop,
// 256 threads all busy in the post-pass, 4-wave barriers).  QBLK=64, 256
// threads, float2 citile, 64-bit store addressing.  Only addition: zeroes
// cnt for its 64 q's (consumed by kernel B's atomics).
// ---------------------------------------------------------------------------
__global__ __launch_bounds__(256) void fused_cost_kernel(
    const float* __restrict__ logits,
    const float* __restrict__ pboxes,
    const float* __restrict__ gboxes,
    const int*   __restrict__ glabels,
    float* __restrict__ out_cost,
    float* __restrict__ out_iou,
    float* __restrict__ piou,
    u64*   __restrict__ pcost,
    int*   __restrict__ ramin,
    int*   __restrict__ cnt)
{
    const int tid = threadIdx.x;
    const int g   = tid & 127;
    const int qh  = tid >> 7;
    const int ci  = blockIdx.x, b = blockIdx.y;

    __shared__ float pq[QCHUNK][16];
    __shared__ int   fgf[QCHUNK];
    __shared__ float lbuf[QCHUNK * 80];          // focal class-cost table
    __shared__ float2 citile[QCHUNK][G_ + 2];    // (cost, iou) per pair

    // zero cnt for this block's 64 q's
    if (tid < QBLK) cnt[b * Q_ + ci * QBLK + tid] = 0;

    // ---- per-thread gt constants (loaded once for all 4 chunks) ----
    const float4* gb4 = (const float4*)(gboxes + ((size_t)b * G_ + g) * 8);
    const float4 gA = gb4[0], gB = gb4[1];
    const float g0 = gA.x, g1 = gA.y, g2 = gA.z, g3 = gA.w;
    const float g4 = gB.x, g5 = gB.y, g6 = gB.z, g7 = gB.w;
    const float gxc = (g0 + g2 + g4 + g6) * 0.25f;
    const float gyc = (g1 + g3 + g5 + g7) * 0.25f;
    const float gw = sqrtf((g0 - g2) * (g0 - g2) + (g1 - g3) * (g1 - g3));
    const float gh = sqrtf((g2 - g4) * (g2 - g4) + (g3 - g5) * (g3 - g5));
    const float gax0 = gxc - gw * 0.5f, gay0 = gyc - gh * 0.5f;
    const float gax1 = gxc + gw * 0.5f, gay1 = gyc + gh * 0.5f;
    const float garea = (gax1 - gax0) * (gay1 - gay0);
    const float v1x = g2 - g0, v1y = g3 - g1, v2x = g4 - g0, v2y = g5 - g1;
    const float gt_area = fabsf(v1x * v2y - v1y * v2x) * 0.5f;
    const float mxx = fmaxf(fmaxf(g0, g2), fmaxf(g4, g6));
    const float mnx = fminf(fminf(g0, g2), fminf(g4, g6));
    const float mxy = fmaxf(fmaxf(g1, g3), fmaxf(g5, g7));
    const float mny = fminf(fminf(g1, g3), fminf(g5, g7));
    const float dgx = mxx - mnx, dgy = mxy - mny;
    const float radius = sqrtf(dgx * dgx + dgy * dgy) / 32.0f;
    const float thresh = gt_area / radius;
    const int lab = glabels[b * G_ + g];

    // running selection state (used by tid<128 threads only)
    float c0 = 1e38f, c1 = 1e38f, c2 = 1e38f, c3 = 1e38f, c4 = 1e38f;
    int   j0 = 0, j1 = 0, j2 = 0, j3 = 0, j4 = 0;
    float t0 = 0.f, t1 = 0.f, t2 = 0.f, t3 = 0.f, t4 = 0.f;

    #pragma unroll 1
    for (int ch = 0; ch < CHPB; ++ch) {
        const int q0 = ci * QBLK + ch * QCHUNK;

        // ---- stage pred boxes (16 q x 8 floats = 32 float4) ----
        if (tid < 32) {
            const float4 v = ((const float4*)(pboxes + ((size_t)b * Q_ + q0) * 8))[tid];
            *(float4*)&pq[tid >> 1][(tid & 1) * 4] = v;
        }
        __syncthreads();
        if (tid < QCHUNK) {
            const float* pr = pq[tid];
            const float p0 = pr[0], p1 = pr[1], p2 = pr[2], p3 = pr[3];
            const float p4 = pr[4], p5v = pr[5], p6 = pr[6], p7 = pr[7];
            const float pxc = (p0 + p2 + p4 + p6) * 0.25f;
            const float pyc = (p1 + p3 + p5v + p7) * 0.25f;
            const float pw = sqrtf((p0 - p2) * (p0 - p2) + (p1 - p3) * (p1 - p3));
            const float ph = sqrtf((p2 - p4) * (p2 - p4) + (p3 - p5v) * (p3 - p5v));
            pq[tid][8]  = pxc;
            pq[tid][9]  = pyc;
            pq[tid][10] = pxc - pw * 0.5f;
            pq[tid][11] = pyc - ph * 0.5f;
            pq[tid][12] = pxc + pw * 0.5f;
            pq[tid][13] = pyc + ph * 0.5f;
            pq[tid][14] = pw * ph;
            fgf[tid] = 0;
        }
        __syncthreads();
        // focal class-cost table for this chunk (16 q x 80 classes)
        for (int j = tid; j < QCHUNK * 80; j += 256)
            lbuf[j] = focal_cost(logits[((size_t)b * Q_ + q0) * 80 + j]);

        // ---- fg mask (any over g); fgf written by lane0 of each wave ----
        const int lane0 = ((tid & 63) == 0);
        for (int i = 0; i < QCHUNK / 2; ++i) {
            const int ql = 2 * i + qh;
            const float dx = pq[ql][8] - gxc, dy = pq[ql][9] - gyc;
            const int in = sqrtf(dx * dx + dy * dy) <= thresh;
            const int anyin = __any(in);
            if (anyin && lane0) fgf[ql] = 1;
        }
        __syncthreads();

        // ---- main loop: full cost + (cost,iou) tile write ----
        #pragma unroll
        for (int jj = 0; jj < 8; ++jj) {
            const int qls = 2 * jj + qh;       // 0..15
            const int q   = q0 + qls;
            const float4 prA = *(const float4*)&pq[qls][0];
            const float4 prB = *(const float4*)&pq[qls][4];
            const float4 prC = *(const float4*)&pq[qls][8];
            const float4 prD = *(const float4*)&pq[qls][12];
            const float p0 = prA.x, p1 = prA.y, p2 = prA.z, p3 = prA.w;
            const float p4 = prB.x, p5v = prB.y, p6 = prB.z, p7 = prB.w;
            const float pxc = prC.x, pyc = prC.y;
            const float pax0 = prC.z, pay0 = prC.w, pax1 = prD.x, pay1 = prD.y;
            const float parea = prD.z;

            const float l1 = fabsf(p0 - g0) + fabsf(p1 - g1) + fabsf(p2 - g2)
                           + fabsf(p3 - g3) + fabsf(p4 - g4) + fabsf(p5v - g5)
                           + fabsf(p6 - g6) + fabsf(p7 - g7);

            const float ltx = fmaxf(pax0, gax0), lty = fmaxf(pay0, gay0);
            const float rbx = fminf(pax1, gax1), rby = fminf(pay1, gay1);
            const float iw = fmaxf(rbx - ltx, 0.f), ih = fmaxf(rby - lty, 0.f);
            const float inter = iw * ih;
            const float iou = inter / (parea + garea - inter + 1e-8f);

            const float ew = fmaxf(pax1, gax1) - fminf(pax0, gax0);
            const float eh = fmaxf(pay1, gay1) - fminf(pay0, gay0);
            const float cc2 = ew * ew + eh * eh + 1e-8f;
            const float dx = pxc - gxc, dy = pyc - gyc;
            const float diou = iou - (dx * dx + dy * dy) / cc2;

            const float cclass = lbuf[qls * 80 + lab];
            const float cost = 5.f * l1 + 2.f * cclass + 2.f * diou
                             + (fgf[qls] ? 0.f : 10000.f);

            const size_t o = ((size_t)b * Q_ + q) * G_ + g;
            out_cost[o] = cost;
            out_iou[o]  = iou;
            citile[qls][g] = make_float2(cost, iou);
        }
        __syncthreads();   // citile complete

        if (tid < G_) {
            // running per-column selection; insert GLOBAL q (ascending order
            // across chunks -> stable strict-< == exact lex tie-break)
            #pragma unroll
            for (int qq = 0; qq < QCHUNK; ++qq) {
                const float2 cv = citile[qq][tid];
                float x = cv.x; int qx = q0 + qq;
                ins_level(c0, j0, x, qx);
                ins_level(c1, j1, x, qx);
                ins_level(c2, j2, x, qx);
                ins_level(c3, j3, x, qx);
                ins_level(c4, j4, x, qx);
                float y = cv.y, m;
                m = fmaxf(t0, y); y = fminf(t0, y); t0 = m;
                m = fmaxf(t1, y); y = fminf(t1, y); t1 = m;
                m = fmaxf(t2, y); y = fminf(t2, y); t2 = m;
                m = fmaxf(t3, y); y = fminf(t3, y); t3 = m;
                t4 = fmaxf(t4, y);
            }
        } else {
            // ---- row argmin (first-index tie-break), 8 lanes per q ----
            const int t    = tid - 128;
            const int part = t & 7;        // 0..7
            const int row  = t >> 3;       // 0..15
            float v = 1e38f; int mg = 0x7fffffff;
            #pragma unroll
            for (int j = 0; j < 16; ++j) {
                const int gg = part + 8 * j;           // ascending per lane
                const float c = citile[row][gg].x;
                if (c < v) { v = c; mg = gg; }         // strict <: first index
            }
            #pragma unroll
            for (int off = 1; off < 8; off <<= 1) {
                const float ov = __shfl_xor(v, off);
                const int   og = __shfl_xor(mg, off);
                if (ov < v || (ov == v && og < mg)) { v = ov; mg = og; }
            }
            if (part == 0) ramin[b * Q_ + q0 + row] = mg;
        }
        // next chunk's first __syncthreads() guards citile reuse
    }

    if (tid < G_) {
        // coalesced layout: [B][NCH][G][5]
        const size_t pbase = (((size_t)b * NCH + ci) * G_ + tid) * 5;
        piou[pbase + 0] = t0; piou[pbase + 1] = t1; piou[pbase + 2] = t2;
        piou[pbase + 3] = t3; piou[pbase + 4] = t4;
        pcost[pbase + 0] = packkey(c0, j0);
        pcost[pbase + 1] = packkey(c1, j1);
        pcost[pbase + 2] = packkey(c2, j2);
        pcost[pbase + 3] = packkey(c3, j3);
        pcost[pbase + 4] = packkey(c4, j4);
    }
}

// ---------------------------------------------------------------------------
// Kernel B: per-column, ONE WAVE (64 threads = one thread per chunk-list):
// butterfly-merge 64 sorted 5-lists -> cand, dyn_k, scatter cnt/gsel.
// 2048 blocks -> fully parallel.
// ---------------------------------------------------------------------------
__global__ __launch_bounds__(64) void dynk_scatter_kernel(
    const u64*   __restrict__ pcost,
    const float* __restrict__ piou,
    u64* __restrict__ cand,
    int* __restrict__ cnt,
    int* __restrict__ gsel)
{
    const int col = blockIdx.x;          // b*G + g
    const int b = col >> 7, g = col & 127;
    const int ln = threadIdx.x;          // = chunk index ci (0..63)

    // layout [B][NCH][G][5]
    const size_t base = (((size_t)b * NCH + ln) * G_ + g) * 5;

    u64 k0 = pcost[base + 0], k1 = pcost[base + 1], k2 = pcost[base + 2],
        k3 = pcost[base + 3], k4 = pcost[base + 4];
    float t0 = piou[base + 0], t1 = piou[base + 1], t2 = piou[base + 2],
          t3 = piou[base + 3], t4 = piou[base + 4];

    #pragma unroll
    for (int off = 1; off < 64; off <<= 1) {
        merge5_asc(k0, k1, k2, k3, k4,
                   __shfl_xor(k0, off), __shfl_xor(k1, off), __shfl_xor(k2, off),
                   __shfl_xor(k3, off), __shfl_xor(k4, off));
        merge5_desc(t0, t1, t2, t3, t4,
                    __shfl_xor(t0, off), __shfl_xor(t1, off), __shfl_xor(t2, off),
                    __shfl_xor(t3, off), __shfl_xor(t4, off));
    }

    if (ln == 0) {
        cand[(size_t)col * 5 + 0] = k0;
        cand[(size_t)col * 5 + 1] = k1;
        cand[(size_t)col * 5 + 2] = k2;
        cand[(size_t)col * 5 + 3] = k3;
        cand[(size_t)col * 5 + 4] = k4;

        const float s = t0 + t1 + t2 + t3 + t4;
        int dynk = (int)s;
        if (dynk < 1) dynk = 1;
        if (dynk > 5) dynk = 5;
        const u64 ks[5] = {k0, k1, k2, k3, k4};
        #pragma unroll
        for (int i = 0; i < 5; ++i) {
            if (i < dynk) {
                const int q = (int)(ks[i] & 0xffffffffu);
                atomicAdd(&cnt[b * Q_ + q], 1);
                gsel[b * Q_ + q] = g;   // only read when cnt==1
            }
        }
    }
}

// ---------------------------------------------------------------------------
// Kernel C: per-batch event-driven refinement loop (1024 threads) — the
// verified round-1 structure.
// ---------------------------------------------------------------------------
__global__ __launch_bounds__(1024) void loop_kernel(
    const float* __restrict__ cost,
    const int* __restrict__ cnt,
    const int* __restrict__ gsel,
    const int* __restrict__ ramin,
    const u64* __restrict__ cand,
    int* __restrict__ rmatch_final)
{
    const int b = blockIdx.x, tid = threadIdx.x;
    const int wv = tid >> 6, ln = tid & 63;

    __shared__ short rmatch[Q_];            // 8 KB
    __shared__ unsigned char s_ra[Q_];      // 4 KB
    __shared__ int newh[Q_];                // 16 KB
    __shared__ unsigned char newg[Q_];      // 4 KB
    __shared__ u64 scand[G_][5];            // 5 KB
    __shared__ int ptrs[G_], col_cnt[G_], unm_list[G_], prop[G_], fb_slot[G_], touched[G_];
    __shared__ int n_unm, n_fb, n_touch;

    for (int q = tid; q < Q_; q += 1024) {
        const int c  = cnt[b * Q_ + q];
        const int ra = ramin[b * Q_ + q];
        s_ra[q] = (unsigned char)ra;
        newh[q] = 0;
        rmatch[q] = (c == 0) ? (short)-1
                             : (c == 1 ? (short)gsel[b * Q_ + q] : (short)ra);
    }
    if (tid < G_) { col_cnt[tid] = 0; ptrs[tid] = 0; }
    if (tid < G_ * 5)
        scand[tid / 5][tid % 5] = cand[(size_t)b * G_ * 5 + tid];
    __syncthreads();
    for (int q = tid; q < Q_; q += 1024)
        if (rmatch[q] >= 0) atomicAdd(&col_cnt[rmatch[q]], 1);
    __syncthreads();

    const float* costb = cost + (size_t)b * Q_ * G_;

    for (int it = 0; it < G_; ++it) {
        if (tid == 0) { n_unm = 0; n_fb = 0; n_touch = 0; }
        __syncthreads();
        if (tid < G_ && col_cnt[tid] == 0)
            unm_list[atomicAdd(&n_unm, 1)] = tid;
        __syncthreads();
        const int nu = n_unm;
        if (nu == 0) break;

        // propose: first unmatched candidate, else mark for fallback scan
        if (tid < nu) {
            const int g = unm_list[tid];
            int p = ptrs[g];
            int q = -1;
            while (p < 5) {
                const int cq = (int)(scand[g][p] & 0xffffffffu);
                if (rmatch[cq] < 0) { q = cq; break; }
                ++p;
            }
            ptrs[g] = p;
            prop[tid] = q;
            if (q < 0) fb_slot[atomicAdd(&n_fb, 1)] = tid;
        }
        __syncthreads();

        // wave-parallel fallback (16 waves): bottom-5 unmatched + refill.
        const int nf = n_fb;
        for (int i = wv; i < nf; i += 16) {
            const int slot = fb_slot[i];
            const int g = unm_list[slot];
            const float* colp = costb + g;
            u64 k0 = U64MAX, k1 = U64MAX, k2 = U64MAX, k3 = U64MAX, k4 = U64MAX;
            for (int q = ln; q < Q_; q += 64) {
                if (rmatch[q] < 0) {
                    const float v = colp[(size_t)q * G_];
                    const u64 kk = packkey(v, q);
                    if (kk < k4) {
                        if (kk < k0)      { k4 = k3; k3 = k2; k2 = k1; k1 = k0; k0 = kk; }
                        else if (kk < k1) { k4 = k3; k3 = k2; k2 = k1; k1 = kk; }
                        else if (kk < k2) { k4 = k3; k3 = k2; k2 = kk; }
                        else if (kk < k3) { k4 = k3; k3 = kk; }
                        else              { k4 = kk; }
                    }
                }
            }
            #pragma unroll
            for (int off = 1; off < 64; off <<= 1) {
                merge5_asc(k0, k1, k2, k3, k4,
                           __shfl_xor(k0, off), __shfl_xor(k1, off), __shfl_xor(k2, off),
                           __shfl_xor(k3, off), __shfl_xor(k4, off));
            }
            if (ln == 0) {
                scand[g][0] = k0; scand[g][1] = k1; scand[g][2] = k2;
                scand[g][3] = k3; scand[g][4] = k4;
                ptrs[g] = 0;
                prop[slot] = (int)(k0 & 0xffffffffu);
            }
        }
        __syncthreads();

        // hits
        if (tid < nu) {
            const int q = prop[tid];
            newg[q] = (unsigned char)unm_list[tid];  // consumed only when nh==1
            if (atomicAdd(&newh[q], 1) == 0)
                touched[atomicAdd(&n_touch, 1)] = q;
        }
        __syncthreads();

        // resolve (dedup): hits only land on unmatched rows
        const int nt = n_touch;
        if (tid < nt) {
            const int q = touched[tid];
            const int nh = newh[q];
            const int gg = (nh == 1) ? (int)newg[q] : (int)s_ra[q];
            rmatch[q] = (short)gg;
            atomicAdd(&col_cnt[gg], 1);
            newh[q] = 0;
        }
        __syncthreads();
    }

    for (int q = tid; q < Q_; q += 1024)
        rmatch_final[b * Q_ + q] = rmatch[q];
}

// ---------------------------------------------------------------------------
// Kernel D: expand rmatch -> full match plane (fully parallel float4 writes).
// ---------------------------------------------------------------------------
__global__ __launch_bounds__(256) void expand_kernel(
    const int* __restrict__ rmatch_final, float* __restrict__ out_match)
{
    const int idx = blockIdx.x * 256 + threadIdx.x;  // float4 index
    const int row = idx >> 5;                        // G/4 = 32 float4 per row
    const int gb  = (idx & 31) << 2;
    const int rm  = rmatch_final[row];
    float4 o;
    o.x = (rm == gb)     ? 1.f : 0.f;
    o.y = (rm == gb + 1) ? 1.f : 0.f;
    o.z = (rm == gb + 2) ? 1.f : 0.f;
    o.w = (rm == gb + 3) ? 1.f : 0.f;
    ((float4*)out_match)[idx] = o;
}

extern "C" void kernel_launch(void* const* d_in, const int* in_sizes, int n_in,
                              void* d_out, int out_size, void* d_ws, size_t ws_size,
                              hipStream_t stream) {
    const float* logits  = (const float*)d_in[0];
    const float* pboxes  = (const float*)d_in[1];
    const float* gboxes  = (const float*)d_in[2];
    const int*   glabels = (const int*)d_in[3];

    float* out = (float*)d_out;
    const size_t BQG = (size_t)B_ * Q_ * G_;
    float* out_match = out;
    float* out_cost  = out + BQG;
    float* out_iou   = out + 2 * BQG;

    // workspace layout (~9 MB)
    char* ws = (char*)d_ws;
    size_t off = 0;
    u64*   pcost  = (u64*)  (ws + off); off += (size_t)B_ * NCH * G_ * 5 * 8;
    float* piou   = (float*)(ws + off); off += (size_t)B_ * NCH * G_ * 5 * 4;
    u64*   cand   = (u64*)  (ws + off); off += (size_t)B_ * G_ * 5 * 8;
    int*   ramin  = (int*)  (ws + off); off += (size_t)B_ * Q_ * 4;
    int*   cnt    = (int*)  (ws + off); off += (size_t)B_ * Q_ * 4;
    int*   gsel   = (int*)  (ws + off); off += (size_t)B_ * Q_ * 4;
    int*   rmf    = (int*)  (ws + off); off += (size_t)B_ * Q_ * 4;

    fused_cost_kernel<<<dim3(NCH, B_), 256, 0, stream>>>(
        logits, pboxes, gboxes, glabels, out_cost, out_iou, piou, pcost, ramin, cnt);
    dynk_scatter_kernel<<<B_ * G_, 64, 0, stream>>>(pcost, piou, cand, cnt, gsel);
    loop_kernel<<<B_, 1024, 0, stream>>>(out_cost, cnt, gsel, ramin, cand, rmf);
    expand_kernel<<<(int)(BQG / 4 / 256), 256, 0, stream>>>(rmf, out_match);
}

// Round 7
// 184.699 us; speedup vs baseline: 1.0550x; 1.0012x over previous
//
#include <hip/hip_runtime.h>
#include <cstdint>
#include <cstddef>

#define B_ 16
#define Q_ 4096
#define G_ 128
#define C_ 80
#define QCHUNK 16
#define QBLK 64                 // q's per A-block (4 chunks)
#define CHPB (QBLK / QCHUNK)    // 4 chunks per block
#define NCH (Q_ / QBLK)         // 64 partial lists per column

typedef unsigned long long u64;
#define U64MAX 0xffffffffffffffffull

// pack (cost,q) into a sortable u64 key: asc key order == lex (cost asc, q asc)
__device__ __forceinline__ u64 packkey(float v, int q) {
    unsigned int bts = __float_as_uint(v);
    if (bts == 0x80000000u) bts = 0u;  // -0.0 -> +0.0
    bts = (bts & 0x80000000u) ? ~bts : (bts | 0x80000000u);
    return ((u64)bts << 32) | (unsigned int)q;
}

__device__ __forceinline__ u64 umin64(u64 a, u64 b) { return a < b ? a : b; }
__device__ __forceinline__ u64 umax64(u64 a, u64 b) { return a > b ? a : b; }

// merge two desc-sorted 5-lists -> top-5 desc (branchless network)
__device__ __forceinline__ void merge5_desc(
    float& a0, float& a1, float& a2, float& a3, float& a4,
    float b0, float b1, float b2, float b3, float b4)
{
    const float r0 = fmaxf(a0, b0);
    const float r1 = fmaxf(fmaxf(a1, b1), fminf(a0, b0));
    const float r2 = fmaxf(fmaxf(a2, b2), fmaxf(fminf(a0, b1), fminf(a1, b0)));
    const float r3 = fmaxf(fmaxf(a3, b3),
                     fmaxf(fminf(a0, b2), fmaxf(fminf(a1, b1), fminf(a2, b0))));
    const float r4 = fmaxf(fmaxf(a4, b4),
                     fmaxf(fmaxf(fminf(a0, b3), fminf(a3, b0)),
                           fmaxf(fminf(a1, b2), fminf(a2, b1))));
    a0 = r0; a1 = r1; a2 = r2; a3 = r3; a4 = r4;
}

// merge two asc-sorted 5-lists of u64 keys -> bottom-5 asc
__device__ __forceinline__ void merge5_asc(
    u64& a0, u64& a1, u64& a2, u64& a3, u64& a4,
    u64 b0, u64 b1, u64 b2, u64 b3, u64 b4)
{
    const u64 r0 = umin64(a0, b0);
    const u64 r1 = umin64(umin64(a1, b1), umax64(a0, b0));
    const u64 r2 = umin64(umin64(a2, b2), umin64(umax64(a0, b1), umax64(a1, b0)));
    const u64 r3 = umin64(umin64(a3, b3),
                   umin64(umax64(a0, b2), umin64(umax64(a1, b1), umax64(a2, b0))));
    const u64 r4 = umin64(umin64(a4, b4),
                   umin64(umin64(umax64(a0, b3), umax64(a3, b0)),
                          umin64(umax64(a1, b2), umax64(a2, b1))));
    a0 = r0; a1 = r1; a2 = r2; a3 = r3; a4 = r4;
}

__device__ __forceinline__ float focal_cost(float x) {
    float p;
    if (x >= 0.f) { const float e = expf(-x); p = 1.f / (1.f + e); }
    else          { const float e = expf(x);  p = e / (1.f + e); }
    const float pos = 0.25f * (1.f - p) * (1.f - p) * (-logf(p + 1e-8f));
    const float neg = 0.75f * p * p * (-logf(1.f - p + 1e-8f));
    return pos - neg;
}

// stable conditional-swap insertion level for (cost,q) lex order (strict <)
__device__ __forceinline__ void ins_level(float& c, int& j, float& x, int& qx) {
    const bool s  = x < c;
    const float nc = s ? x : c;
    const float nx = s ? c : x;
    const int   nj = s ? qx : j;
    const int   nq = s ? j : qx;
    c = nc; x = nx; j = nj; qx = nq;
}

// ---------------------------------------------------------------------------
// Kernel A: fused cost/iou + focal, FUSED-INSERT structure.  Measured
// invariant (R3-R6): VALU-issue time ~41us regardless of shape; the old
// post-pass ran a 560-op selection on waves 0-1 while waves 2-3 idled
// (~1205-op critical path).  Now each thread inserts its own column's
// (cost,iou) into REGISTER lists inside the pair loop (8 elems, own g),
// the two q-parity halves merge once at kernel end via packed-key
// merge5 through LDS (rounds-0-2-verified mechanism), and the argmin
// post-pass uses a cost-only b32 tile reduced by ALL 256 threads.
// Balanced ~800-op critical path, one less barrier, no s_iou tile.
// ---------------------------------------------------------------------------
__global__ __launch_bounds__(256) void fused_cost_kernel(
    const float* __restrict__ logits,
    const float* __restrict__ pboxes,
    const float* __restrict__ gboxes,
    const int*   __restrict__ glabels,
    float* __restrict__ out_cost,
    float* __restrict__ out_iou,
    float* __restrict__ piou,
    u64*   __restrict__ pcost,
    int*   __restrict__ ramin,
    int*   __restrict__ cnt)
{
    const int tid = threadIdx.x;
    const int g   = tid & 127;
    const int qh  = tid >> 7;            // q parity: 0 = even q, 1 = odd q
    const int ci  = blockIdx.x, b = blockIdx.y;

    __shared__ float pq[QCHUNK][16];
    __shared__ int   fgf[QCHUNK];
    __shared__ float lbuf[QCHUNK * 80];          // focal class-cost table
    __shared__ float s_cost[QCHUNK][G_ + 1];     // cost tile (argmin only)
    __shared__ u64   khalf[G_][5];               // qh=1 cost keys
    __shared__ float phalf[G_][5];               // qh=1 iou top-5

    // zero cnt for this block's 64 q's
    if (tid < QBLK) cnt[b * Q_ + ci * QBLK + tid] = 0;

    // ---- per-thread gt constants (loaded once for all 4 chunks) ----
    const float4* gb4 = (const float4*)(gboxes + ((size_t)b * G_ + g) * 8);
    const float4 gA = gb4[0], gB = gb4[1];
    const float g0 = gA.x, g1 = gA.y, g2 = gA.z, g3 = gA.w;
    const float g4 = gB.x, g5 = gB.y, g6 = gB.z, g7 = gB.w;
    const float gxc = (g0 + g2 + g4 + g6) * 0.25f;
    const float gyc = (g1 + g3 + g5 + g7) * 0.25f;
    const float gw = sqrtf((g0 - g2) * (g0 - g2) + (g1 - g3) * (g1 - g3));
    const float gh = sqrtf((g2 - g4) * (g2 - g4) + (g3 - g5) * (g3 - g5));
    const float gax0 = gxc - gw * 0.5f, gay0 = gyc - gh * 0.5f;
    const float gax1 = gxc + gw * 0.5f, gay1 = gyc + gh * 0.5f;
    const float garea = (gax1 - gax0) * (gay1 - gay0);
    const float v1x = g2 - g0, v1y = g3 - g1, v2x = g4 - g0, v2y = g5 - g1;
    const float gt_area = fabsf(v1x * v2y - v1y * v2x) * 0.5f;
    const float mxx = fmaxf(fmaxf(g0, g2), fmaxf(g4, g6));
    const float mnx = fminf(fminf(g0, g2), fminf(g4, g6));
    const float mxy = fmaxf(fmaxf(g1, g3), fmaxf(g5, g7));
    const float mny = fminf(fminf(g1, g3), fminf(g5, g7));
    const float dgx = mxx - mnx, dgy = mxy - mny;
    const float radius = sqrtf(dgx * dgx + dgy * dgy) / 32.0f;
    const float thresh = gt_area / radius;
    const int lab = glabels[b * G_ + g];

    // per-thread running selection state over this thread's 32 q's (own g)
    float c0 = 1e38f, c1 = 1e38f, c2 = 1e38f, c3 = 1e38f, c4 = 1e38f;
    int   j0 = 0, j1 = 0, j2 = 0, j3 = 0, j4 = 0;
    float t0 = 0.f, t1 = 0.f, t2 = 0.f, t3 = 0.f, t4 = 0.f;

    #pragma unroll 1
    for (int ch = 0; ch < CHPB; ++ch) {
        const int q0 = ci * QBLK + ch * QCHUNK;

        // ---- stage pred boxes (16 q x 8 floats = 32 float4) ----
        if (tid < 32) {
            const float4 v = ((const float4*)(pboxes + ((size_t)b * Q_ + q0) * 8))[tid];
            *(float4*)&pq[tid >> 1][(tid & 1) * 4] = v;
        }
        __syncthreads();
        if (tid < QCHUNK) {
            const float* pr = pq[tid];
            const float p0 = pr[0], p1 = pr[1], p2 = pr[2], p3 = pr[3];
            const float p4 = pr[4], p5v = pr[5], p6 = pr[6], p7 = pr[7];
            const float pxc = (p0 + p2 + p4 + p6) * 0.25f;
            const float pyc = (p1 + p3 + p5v + p7) * 0.25f;
            const float pw = sqrtf((p0 - p2) * (p0 - p2) + (p1 - p3) * (p1 - p3));
            const float ph = sqrtf((p2 - p4) * (p2 - p4) + (p3 - p5v) * (p3 - p5v));
            pq[tid][8]  = pxc;
            pq[tid][9]  = pyc;
            pq[tid][10] = pxc - pw * 0.5f;
            pq[tid][11] = pyc - ph * 0.5f;
            pq[tid][12] = pxc + pw * 0.5f;
            pq[tid][13] = pyc + ph * 0.5f;
            pq[tid][14] = pw * ph;
            fgf[tid] = 0;
        }
        __syncthreads();
        // focal class-cost table for this chunk (16 q x 80 classes)
        for (int j = tid; j < QCHUNK * 80; j += 256)
            lbuf[j] = focal_cost(logits[((size_t)b * Q_ + q0) * 80 + j]);

        // ---- fg mask (any over g); fgf written by lane0 of each wave ----
        const int lane0 = ((tid & 63) == 0);
        for (int i = 0; i < QCHUNK / 2; ++i) {
            const int ql = 2 * i + qh;
            const float dx = pq[ql][8] - gxc, dy = pq[ql][9] - gyc;
            const int in = sqrtf(dx * dx + dy * dy) <= thresh;
            const int anyin = __any(in);
            if (anyin && lane0) fgf[ql] = 1;
        }
        __syncthreads();

        // ---- main loop: cost/iou + register-list inserts (own column g) ----
        int o = (b * Q_ + q0 + qh) * G_ + g;     // fits in int (max ~8.4M)
        #pragma unroll
        for (int jj = 0; jj < 8; ++jj) {
            const int qls = 2 * jj + qh;       // 0..15
            const int q   = q0 + qls;
            const float4 prA = *(const float4*)&pq[qls][0];
            const float4 prB = *(const float4*)&pq[qls][4];
            const float4 prC = *(const float4*)&pq[qls][8];
            const float4 prD = *(const float4*)&pq[qls][12];
            const float p0 = prA.x, p1 = prA.y, p2 = prA.z, p3 = prA.w;
            const float p4 = prB.x, p5v = prB.y, p6 = prB.z, p7 = prB.w;
            const float pxc = prC.x, pyc = prC.y;
            const float pax0 = prC.z, pay0 = prC.w, pax1 = prD.x, pay1 = prD.y;
            const float parea = prD.z;

            const float l1 = fabsf(p0 - g0) + fabsf(p1 - g1) + fabsf(p2 - g2)
                           + fabsf(p3 - g3) + fabsf(p4 - g4) + fabsf(p5v - g5)
                           + fabsf(p6 - g6) + fabsf(p7 - g7);

            const float ltx = fmaxf(pax0, gax0), lty = fmaxf(pay0, gay0);
            const float rbx = fminf(pax1, gax1), rby = fminf(pay1, gay1);
            const float iw = fmaxf(rbx - ltx, 0.f), ih = fmaxf(rby - lty, 0.f);
            const float inter = iw * ih;
            const float iou = inter / (parea + garea - inter + 1e-8f);

            const float ew = fmaxf(pax1, gax1) - fminf(pax0, gax0);
            const float eh = fmaxf(pay1, gay1) - fminf(pay0, gay0);
            const float cc2 = ew * ew + eh * eh + 1e-8f;
            const float dx = pxc - gxc, dy = pyc - gyc;
            const float diou = iou - (dx * dx + dy * dy) / cc2;

            const float cclass = lbuf[qls * 80 + lab];
            const float cost = 5.f * l1 + 2.f * cclass + 2.f * diou
                             + (fgf[qls] ? 0.f : 10000.f);

            out_cost[o] = cost;
            out_iou[o]  = iou;
            o += 2 * G_;
            s_cost[qls][g] = cost;

            // bottom-5 (cost, global q) lex insert: q's ascending per thread,
            // stable strict-< keeps smaller q ahead on ties
            { float x = cost; int qx = q;
              ins_level(c0, j0, x, qx);
              ins_level(c1, j1, x, qx);
              ins_level(c2, j2, x, qx);
              ins_level(c3, j3, x, qx);
              ins_level(c4, j4, x, qx); }
            // top-5 iou insert
            { float y = iou, m;
              m = fmaxf(t0, y); y = fminf(t0, y); t0 = m;
              m = fmaxf(t1, y); y = fminf(t1, y); t1 = m;
              m = fmaxf(t2, y); y = fminf(t2, y); t2 = m;
              m = fmaxf(t3, y); y = fminf(t3, y); t3 = m;
              t4 = fmaxf(t4, y); }
        }
        __syncthreads();   // s_cost complete

        // ---- row argmin (first-index tie-break), ALL 256 threads:
        //      16 lanes per row, each scans g = part + 16j ascending ----
        {
            const int part = tid & 15;     // 0..15
            const int row  = tid >> 4;     // 0..15
            float v = 1e38f; int mg = 0x7fffffff;
            #pragma unroll
            for (int j = 0; j < 8; ++j) {
                const int gg = part + 16 * j;          // ascending per lane
                const float c = s_cost[row][gg];
                if (c < v) { v = c; mg = gg; }         // strict <: first index
            }
            #pragma unroll
            for (int off = 1; off < 16; off <<= 1) {
                const float ov = __shfl_xor(v, off);
                const int   og = __shfl_xor(mg, off);
                if (ov < v || (ov == v && og < mg)) { v = ov; mg = og; }
            }
            if (part == 0) ramin[b * Q_ + q0 + row] = mg;
        }
        // no barrier: 3 barriers precede the next chunk's s_cost overwrite
    }

    // ---- merge q-parity halves, write per (b, ci, g) partial lists ----
    if (qh == 1) {
        khalf[g][0] = packkey(c0, j0); khalf[g][1] = packkey(c1, j1);
        khalf[g][2] = packkey(c2, j2); khalf[g][3] = packkey(c3, j3);
        khalf[g][4] = packkey(c4, j4);
        phalf[g][0] = t0; phalf[g][1] = t1; phalf[g][2] = t2;
        phalf[g][3] = t3; phalf[g][4] = t4;
    }
    __syncthreads();
    if (qh == 0) {
        u64 a0 = packkey(c0, j0), a1 = packkey(c1, j1), a2 = packkey(c2, j2),
            a3 = packkey(c3, j3), a4 = packkey(c4, j4);
        merge5_asc(a0, a1, a2, a3, a4,
                   khalf[g][0], khalf[g][1], khalf[g][2], khalf[g][3], khalf[g][4]);
        merge5_desc(t0, t1, t2, t3, t4,
                    phalf[g][0], phalf[g][1], phalf[g][2], phalf[g][3], phalf[g][4]);
        // coalesced layout: [B][NCH][G][5]
        const size_t pbase = (((size_t)b * NCH + ci) * G_ + g) * 5;
        piou[pbase + 0] = t0; piou[pbase + 1] = t1; piou[pbase + 2] = t2;
        piou[pbase + 3] = t3; piou[pbase + 4] = t4;
        pcost[pbase + 0] = a0; pcost[pbase + 1] = a1; pcost[pbase + 2] = a2;
        pcost[pbase + 3] = a3; pcost[pbase + 4] = a4;
    }
}

// ---------------------------------------------------------------------------
// Kernel B: per-column, ONE WAVE (64 threads = one thread per chunk-list):
// butterfly-merge 64 sorted 5-lists -> cand, dyn_k, scatter cnt/gsel.
// ---------------------------------------------------------------------------
__global__ __launch_bounds__(64) void dynk_scatter_kernel(
    const u64*   __restrict__ pcost,
    const float* __restrict__ piou,
    u64* __restrict__ cand,
    int* __restrict__ cnt,
    int* __restrict__ gsel)
{
    const int col = blockIdx.x;          // b*G + g
    const int b = col >> 7, g = col & 127;
    const int ln = threadIdx.x;          // = chunk index ci (0..63)

    // layout [B][NCH][G][5]
    const size_t base = (((size_t)b * NCH + ln) * G_ + g) * 5;

    u64 k0 = pcost[base + 0], k1 = pcost[base + 1], k2 = pcost[base + 2],
        k3 = pcost[base + 3], k4 = pcost[base + 4];
    float t0 = piou[base + 0], t1 = piou[base + 1], t2 = piou[base + 2],
          t3 = piou[base + 3], t4 = piou[base + 4];

    #pragma unroll
    for (int off = 1; off < 64; off <<= 1) {
        merge5_asc(k0, k1, k2, k3, k4,
                   __shfl_xor(k0, off), __shfl_xor(k1, off), __shfl_xor(k2, off),
                   __shfl_xor(k3, off), __shfl_xor(k4, off));
        merge5_desc(t0, t1, t2, t3, t4,
                    __shfl_xor(t0, off), __shfl_xor(t1, off), __shfl_xor(t2, off),
                    __shfl_xor(t3, off), __shfl_xor(t4, off));
    }

    if (ln == 0) {
        cand[(size_t)col * 5 + 0] = k0;
        cand[(size_t)col * 5 + 1] = k1;
        cand[(size_t)col * 5 + 2] = k2;
        cand[(size_t)col * 5 + 3] = k3;
        cand[(size_t)col * 5 + 4] = k4;

        const float s = t0 + t1 + t2 + t3 + t4;
        int dynk = (int)s;
        if (dynk < 1) dynk = 1;
        if (dynk > 5) dynk = 5;
        const u64 ks[5] = {k0, k1, k2, k3, k4};
        #pragma unroll
        for (int i = 0; i < 5; ++i) {
            if (i < dynk) {
                const int q = (int)(ks[i] & 0xffffffffu);
                atomicAdd(&cnt[b * Q_ + q], 1);
                gsel[b * Q_ + q] = g;   // only read when cnt==1
            }
        }
    }
}

// ---------------------------------------------------------------------------
// Kernel C: per-batch event-driven refinement loop (1024 threads) — the
// verified round-1 structure.
// ---------------------------------------------------------------------------
__global__ __launch_bounds__(1024) void loop_kernel(
    const float* __restrict__ cost,
    const int* __restrict__ cnt,
    const int* __restrict__ gsel,
    const int* __restrict__ ramin,
    const u64* __restrict__ cand,
    int* __restrict__ rmatch_final)
{
    const int b = blockIdx.x, tid = threadIdx.x;
    const int wv = tid >> 6, ln = tid & 63;

    __shared__ short rmatch[Q_];            // 8 KB
    __shared__ unsigned char s_ra[Q_];      // 4 KB
    __shared__ int newh[Q_];                // 16 KB
    __shared__ unsigned char newg[Q_];      // 4 KB
    __shared__ u64 scand[G_][5];            // 5 KB
    __shared__ int ptrs[G_], col_cnt[G_], unm_list[G_], prop[G_], fb_slot[G_], touched[G_];
    __shared__ int n_unm, n_fb, n_touch;

    for (int q = tid; q < Q_; q += 1024) {
        const int c  = cnt[b * Q_ + q];
        const int ra = ramin[b * Q_ + q];
        s_ra[q] = (unsigned char)ra;
        newh[q] = 0;
        rmatch[q] = (c == 0) ? (short)-1
                             : (c == 1 ? (short)gsel[b * Q_ + q] : (short)ra);
    }
    if (tid < G_) { col_cnt[tid] = 0; ptrs[tid] = 0; }
    if (tid < G_ * 5)
        scand[tid / 5][tid % 5] = cand[(size_t)b * G_ * 5 + tid];
    __syncthreads();
    for (int q = tid; q < Q_; q += 1024)
        if (rmatch[q] >= 0) atomicAdd(&col_cnt[rmatch[q]], 1);
    __syncthreads();

    const float* costb = cost + (size_t)b * Q_ * G_;

    for (int it = 0; it < G_; ++it) {
        if (tid == 0) { n_unm = 0; n_fb = 0; n_touch = 0; }
        __syncthreads();
        if (tid < G_ && col_cnt[tid] == 0)
            unm_list[atomicAdd(&n_unm, 1)] = tid;
        __syncthreads();
        const int nu = n_unm;
        if (nu == 0) break;

        // propose: first unmatched candidate, else mark for fallback scan
        if (tid < nu) {
            const int g = unm_list[tid];
            int p = ptrs[g];
            int q = -1;
            while (p < 5) {
                const int cq = (int)(scand[g][p] & 0xffffffffu);
                if (rmatch[cq] < 0) { q = cq; break; }
                ++p;
            }
            ptrs[g] = p;
            prop[tid] = q;
            if (q < 0) fb_slot[atomicAdd(&n_fb, 1)] = tid;
        }
        __syncthreads();

        // wave-parallel fallback (16 waves): bottom-5 unmatched + refill.
        const int nf = n_fb;
        for (int i = wv; i < nf; i += 16) {
            const int slot = fb_slot[i];
            const int g = unm_list[slot];
            const float* colp = costb + g;
            u64 k0 = U64MAX, k1 = U64MAX, k2 = U64MAX, k3 = U64MAX, k4 = U64MAX;
            for (int q = ln; q < Q_; q += 64) {
                if (rmatch[q] < 0) {
                    const float v = colp[(size_t)q * G_];
                    const u64 kk = packkey(v, q);
                    if (kk < k4) {
                        if (kk < k0)      { k4 = k3; k3 = k2; k2 = k1; k1 = k0; k0 = kk; }
                        else if (kk < k1) { k4 = k3; k3 = k2; k2 = k1; k1 = kk; }
                        else if (kk < k2) { k4 = k3; k3 = k2; k2 = kk; }
                        else if (kk < k3) { k4 = k3; k3 = kk; }
                        else              { k4 = kk; }
                    }
                }
            }
            #pragma unroll
            for (int off = 1; off < 64; off <<= 1) {
                merge5_asc(k0, k1, k2, k3, k4,
                           __shfl_xor(k0, off), __shfl_xor(k1, off), __shfl_xor(k2, off),
                           __shfl_xor(k3, off), __shfl_xor(k4, off));
            }
            if (ln == 0) {
                scand[g][0] = k0; scand[g][1] = k1; scand[g][2] = k2;
                scand[g][3] = k3; scand[g][4] = k4;
                ptrs[g] = 0;
                prop[slot] = (int)(k0 & 0xffffffffu);
            }
        }
        __syncthreads();

        // hits
        if (tid < nu) {
            const int q = prop[tid];
            newg[q] = (unsigned char)unm_list[tid];  // consumed only when nh==1
            if (atomicAdd(&newh[q], 1) == 0)
                touched[atomicAdd(&n_touch, 1)] = q;
        }
        __syncthreads();

        // resolve (dedup): hits only land on unmatched rows
        const int nt = n_touch;
        if (tid < nt) {
            const int q = touched[tid];
            const int nh = newh[q];
            const int gg = (nh == 1) ? (int)newg[q] : (int)s_ra[q];
            rmatch[q] = (short)gg;
            atomicAdd(&col_cnt[gg], 1);
            newh[q] = 0;
        }
        __syncthreads();
    }

    for (int q = tid; q < Q_; q += 1024)
        rmatch_final[b * Q_ + q] = rmatch[q];
}

// ---------------------------------------------------------------------------
// Kernel D: expand rmatch -> full match plane (fully parallel float4 writes).
// ---------------------------------------------------------------------------
__global__ __launch_bounds__(256) void expand_kernel(
    const int* __restrict__ rmatch_final, float* __restrict__ out_match)
{
    const int idx = blockIdx.x * 256 + threadIdx.x;  // float4 index
    const int row = idx >> 5;                        // G/4 = 32 float4 per row
    const int gb  = (idx & 31) << 2;
    const int rm  = rmatch_final[row];
    float4 o;
    o.x = (rm == gb)     ? 1.f : 0.f;
    o.y = (rm == gb + 1) ? 1.f : 0.f;
    o.z = (rm == gb + 2) ? 1.f : 0.f;
    o.w = (rm == gb + 3) ? 1.f : 0.f;
    ((float4*)out_match)[idx] = o;
}

extern "C" void kernel_launch(void* const* d_in, const int* in_sizes, int n_in,
                              void* d_out, int out_size, void* d_ws, size_t ws_size,
                              hipStream_t stream) {
    const float* logits  = (const float*)d_in[0];
    const float* pboxes  = (const float*)d_in[1];
    const float* gboxes  = (const float*)d_in[2];
    const int*   glabels = (const int*)d_in[3];

    float* out = (float*)d_out;
    const size_t BQG = (size_t)B_ * Q_ * G_;
    float* out_match = out;
    float* out_cost  = out + BQG;
    float* out_iou   = out + 2 * BQG;

    // workspace layout (~9 MB)
    char* ws = (char*)d_ws;
    size_t off = 0;
    u64*   pcost  = (u64*)  (ws + off); off += (size_t)B_ * NCH * G_ * 5 * 8;
    float* piou   = (float*)(ws + off); off += (size_t)B_ * NCH * G_ * 5 * 4;
    u64*   cand   = (u64*)  (ws + off); off += (size_t)B_ * G_ * 5 * 8;
    int*   ramin  = (int*)  (ws + off); off += (size_t)B_ * Q_ * 4;
    int*   cnt    = (int*)  (ws + off); off += (size_t)B_ * Q_ * 4;
    int*   gsel   = (int*)  (ws + off); off += (size_t)B_ * Q_ * 4;
    int*   rmf    = (int*)  (ws + off); off += (size_t)B_ * Q_ * 4;

    fused_cost_kernel<<<dim3(NCH, B_), 256, 0, stream>>>(
        logits, pboxes, gboxes, glabels, out_cost, out_iou, piou, pcost, ramin, cnt);
    dynk_scatter_kernel<<<B_ * G_, 64, 0, stream>>>(pcost, piou, cand, cnt, gsel);
    loop_kernel<<<B_, 1024, 0, stream>>>(out_cost, cnt, gsel, ramin, cand, rmf);
    expand_kernel<<<(int)(BQG / 4 / 256), 256, 0, stream>>>(rmf, out_match);
}

// Round 8
// 178.530 us; speedup vs baseline: 1.0915x; 1.0346x over previous
//
#include <hip/hip_runtime.h>
#include <cstdint>
#include <cstddef>

#define B_ 16
#define Q_ 4096
#define G_ 128
#define C_ 80
#define QCHUNK 16
#define QBLK 64                 // q's per A-block (4 chunks)
#define CHPB (QBLK / QCHUNK)    // 4 chunks per block
#define NCH (Q_ / QBLK)         // 64 partial lists per column

typedef unsigned long long u64;
#define U64MAX 0xffffffffffffffffull

// pack (cost,q) into a sortable u64 key: asc key order == lex (cost asc, q asc)
__device__ __forceinline__ u64 packkey(float v, int q) {
    unsigned int bts = __float_as_uint(v);
    if (bts == 0x80000000u) bts = 0u;  // -0.0 -> +0.0
    bts = (bts & 0x80000000u) ? ~bts : (bts | 0x80000000u);
    return ((u64)bts << 32) | (unsigned int)q;
}

__device__ __forceinline__ u64 umin64(u64 a, u64 b) { return a < b ? a : b; }
__device__ __forceinline__ u64 umax64(u64 a, u64 b) { return a > b ? a : b; }

// merge two desc-sorted 5-lists -> top-5 desc (branchless network)
__device__ __forceinline__ void merge5_desc(
    float& a0, float& a1, float& a2, float& a3, float& a4,
    float b0, float b1, float b2, float b3, float b4)
{
    const float r0 = fmaxf(a0, b0);
    const float r1 = fmaxf(fmaxf(a1, b1), fminf(a0, b0));
    const float r2 = fmaxf(fmaxf(a2, b2), fmaxf(fminf(a0, b1), fminf(a1, b0)));
    const float r3 = fmaxf(fmaxf(a3, b3),
                     fmaxf(fminf(a0, b2), fmaxf(fminf(a1, b1), fminf(a2, b0))));
    const float r4 = fmaxf(fmaxf(a4, b4),
                     fmaxf(fmaxf(fminf(a0, b3), fminf(a3, b0)),
                           fmaxf(fminf(a1, b2), fminf(a2, b1))));
    a0 = r0; a1 = r1; a2 = r2; a3 = r3; a4 = r4;
}

// merge two asc-sorted 5-lists of u64 keys -> bottom-5 asc
__device__ __forceinline__ void merge5_asc(
    u64& a0, u64& a1, u64& a2, u64& a3, u64& a4,
    u64 b0, u64 b1, u64 b2, u64 b3, u64 b4)
{
    const u64 r0 = umin64(a0, b0);
    const u64 r1 = umin64(umin64(a1, b1), umax64(a0, b0));
    const u64 r2 = umin64(umin64(a2, b2), umin64(umax64(a0, b1), umax64(a1, b0)));
    const u64 r3 = umin64(umin64(a3, b3),
                   umin64(umax64(a0, b2), umin64(umax64(a1, b1), umax64(a2, b0))));
    const u64 r4 = umin64(umin64(a4, b4),
                   umin64(umin64(umax64(a0, b3), umax64(a3, b0)),
                          umin64(umax64(a1, b2), umax64(a2, b1))));
    a0 = r0; a1 = r1; a2 = r2; a3 = r3; a4 = r4;
}

__device__ __forceinline__ float focal_cost(float x) {
    float p;
    if (x >= 0.f) { const float e = expf(-x); p = 1.f / (1.f + e); }
    else          { const float e = expf(x);  p = e / (1.f + e); }
    const float pos = 0.25f * (1.f - p) * (1.f - p) * (-logf(p + 1e-8f));
    const float neg = 0.75f * p * p * (-logf(1.f - p + 1e-8f));
    return pos - neg;
}

// stable conditional-swap insertion level for (cost,q) lex order (strict <)
__device__ __forceinline__ void ins_level(float& c, int& j, float& x, int& qx) {
    const bool s  = x < c;
    const float nc = s ? x : c;
    const float nx = s ? c : x;
    const int   nj = s ? qx : j;
    const int   nq = s ? j : qx;
    c = nc; x = nx; j = nj; qx = nq;
}

// ---------------------------------------------------------------------------
// Kernel A: fused cost/iou + focal, HOISTED-STAGING structure.  R7 measured:
// VALU-issue time ~40us (op-count invariant), VALUBusy 63% -- the remaining
// 37% is phase/barrier overhead from re-staging pboxes/focal/fg per chunk
// (17 barriers, 4 serialized stage chains).  Now ALL 64 q's are staged,
// derived, fg-masked, and focal-tabled ONCE (lbuf 64x80 = 20.5KB; LDS total
// ~33KB -> still 4 blocks/CU = grid limit), and the chunk loop is pure
// compute: {8 pairs -> barrier -> argmin -> barrier} = 12 barriers total.
// khalf/phalf overlay s_cost (written only after last argmin).  Selection /
// argmin / parity-merge mechanisms identical to R7 (verified passing).
// ---------------------------------------------------------------------------
__global__ __launch_bounds__(256) void fused_cost_kernel(
    const float* __restrict__ logits,
    const float* __restrict__ pboxes,
    const float* __restrict__ gboxes,
    const int*   __restrict__ glabels,
    float* __restrict__ out_cost,
    float* __restrict__ out_iou,
    float* __restrict__ piou,
    u64*   __restrict__ pcost,
    int*   __restrict__ ramin,
    int*   __restrict__ cnt)
{
    const int tid = threadIdx.x;
    const int g   = tid & 127;
    const int qh  = tid >> 7;            // q parity: 0 = even q, 1 = odd q
    const int ci  = blockIdx.x, b = blockIdx.y;
    const int qb0 = ci * QBLK;

    __shared__ float pq[QBLK][16];               // 4 KB: all 64 q's staged
    __shared__ int   fgf[QBLK];                  // 256 B
    __shared__ float lbuf[QBLK * 80];            // 20.5 KB: focal for 64 q's
    // overlay: s_cost (argmin tile, per chunk) and khalf/phalf (final merge)
    __shared__ __align__(16) char ovl[QCHUNK * (G_ + 1) * 4];  // 8256 B
    float (*s_cost)[G_ + 1] = (float(*)[G_ + 1])ovl;
    u64   (*khalf)[5]       = (u64(*)[5])ovl;                  // 5120 B
    float (*phalf)[5]       = (float(*)[5])(ovl + 5120);       // 2560 B

    // ---- P1: stage all 64 q's pred boxes (128 float4); zero cnt/fgf ----
    if (tid < 128) {
        const float4 v = ((const float4*)(pboxes + ((size_t)b * Q_ + qb0) * 8))[tid];
        *(float4*)&pq[tid >> 1][(tid & 1) * 4] = v;
    } else if (tid < 128 + QBLK) {
        cnt[b * Q_ + qb0 + (tid - 128)] = 0;
        fgf[tid - 128] = 0;
    }

    // ---- per-thread gt constants ----
    const float4* gb4 = (const float4*)(gboxes + ((size_t)b * G_ + g) * 8);
    const float4 gA = gb4[0], gB = gb4[1];
    const float g0 = gA.x, g1 = gA.y, g2 = gA.z, g3 = gA.w;
    const float g4 = gB.x, g5 = gB.y, g6 = gB.z, g7 = gB.w;
    const float gxc = (g0 + g2 + g4 + g6) * 0.25f;
    const float gyc = (g1 + g3 + g5 + g7) * 0.25f;
    const float gw = sqrtf((g0 - g2) * (g0 - g2) + (g1 - g3) * (g1 - g3));
    const float gh = sqrtf((g2 - g4) * (g2 - g4) + (g3 - g5) * (g3 - g5));
    const float gax0 = gxc - gw * 0.5f, gay0 = gyc - gh * 0.5f;
    const float gax1 = gxc + gw * 0.5f, gay1 = gyc + gh * 0.5f;
    const float garea = (gax1 - gax0) * (gay1 - gay0);
    const float v1x = g2 - g0, v1y = g3 - g1, v2x = g4 - g0, v2y = g5 - g1;
    const float gt_area = fabsf(v1x * v2y - v1y * v2x) * 0.5f;
    const float mxx = fmaxf(fmaxf(g0, g2), fmaxf(g4, g6));
    const float mnx = fminf(fminf(g0, g2), fminf(g4, g6));
    const float mxy = fmaxf(fmaxf(g1, g3), fmaxf(g5, g7));
    const float mny = fminf(fminf(g1, g3), fminf(g5, g7));
    const float dgx = mxx - mnx, dgy = mxy - mny;
    const float radius = sqrtf(dgx * dgx + dgy * dgy) / 32.0f;
    const float thresh = gt_area / radius;
    const int lab = glabels[b * G_ + g];

    __syncthreads();   // P1 done

    // ---- P2: derive (tid<64, one row each) + focal table (all threads) ----
    if (tid < QBLK) {
        const float* pr = pq[tid];
        const float p0 = pr[0], p1 = pr[1], p2 = pr[2], p3 = pr[3];
        const float p4 = pr[4], p5v = pr[5], p6 = pr[6], p7 = pr[7];
        const float pxc = (p0 + p2 + p4 + p6) * 0.25f;
        const float pyc = (p1 + p3 + p5v + p7) * 0.25f;
        const float pw = sqrtf((p0 - p2) * (p0 - p2) + (p1 - p3) * (p1 - p3));
        const float ph = sqrtf((p2 - p4) * (p2 - p4) + (p3 - p5v) * (p3 - p5v));
        pq[tid][8]  = pxc;
        pq[tid][9]  = pyc;
        pq[tid][10] = pxc - pw * 0.5f;
        pq[tid][11] = pyc - ph * 0.5f;
        pq[tid][12] = pxc + pw * 0.5f;
        pq[tid][13] = pyc + ph * 0.5f;
        pq[tid][14] = pw * ph;
    }
    for (int j = tid; j < QBLK * 80; j += 256)
        lbuf[j] = focal_cost(logits[((size_t)b * Q_ + qb0) * 80 + j]);
    __syncthreads();   // P2 done

    // ---- P3: fg mask for all 64 q's (wave-halved OR accumulation) ----
    {
        const int lane0 = ((tid & 63) == 0);
        for (int i = 0; i < QBLK / 2; ++i) {
            const int ql = 2 * i + qh;
            const float dx = pq[ql][8] - gxc, dy = pq[ql][9] - gyc;
            const int in = sqrtf(dx * dx + dy * dy) <= thresh;
            const int anyin = __any(in);
            if (anyin && lane0) fgf[ql] = 1;
        }
    }
    __syncthreads();   // P3 done

    // per-thread running selection state over this thread's 32 q's (own g)
    float c0 = 1e38f, c1 = 1e38f, c2 = 1e38f, c3 = 1e38f, c4 = 1e38f;
    int   j0 = 0, j1 = 0, j2 = 0, j3 = 0, j4 = 0;
    float t0 = 0.f, t1 = 0.f, t2 = 0.f, t3 = 0.f, t4 = 0.f;

    #pragma unroll 1
    for (int ch = 0; ch < CHPB; ++ch) {
        const int q0 = qb0 + ch * QCHUNK;

        // ---- main loop: cost/iou + register-list inserts (own column g) ----
        int o = (b * Q_ + q0 + qh) * G_ + g;     // fits in int
        #pragma unroll
        for (int jj = 0; jj < 8; ++jj) {
            const int qls  = 2 * jj + qh;        // 0..15 within chunk
            const int qrow = ch * QCHUNK + qls;  // 0..63 staged row
            const int q    = q0 + qls;
            const float4 prA = *(const float4*)&pq[qrow][0];
            const float4 prB = *(const float4*)&pq[qrow][4];
            const float4 prC = *(const float4*)&pq[qrow][8];
            const float4 prD = *(const float4*)&pq[qrow][12];
            const float p0 = prA.x, p1 = prA.y, p2 = prA.z, p3 = prA.w;
            const float p4 = prB.x, p5v = prB.y, p6 = prB.z, p7 = prB.w;
            const float pxc = prC.x, pyc = prC.y;
            const float pax0 = prC.z, pay0 = prC.w, pax1 = prD.x, pay1 = prD.y;
            const float parea = prD.z;

            const float l1 = fabsf(p0 - g0) + fabsf(p1 - g1) + fabsf(p2 - g2)
                           + fabsf(p3 - g3) + fabsf(p4 - g4) + fabsf(p5v - g5)
                           + fabsf(p6 - g6) + fabsf(p7 - g7);

            const float ltx = fmaxf(pax0, gax0), lty = fmaxf(pay0, gay0);
            const float rbx = fminf(pax1, gax1), rby = fminf(pay1, gay1);
            const float iw = fmaxf(rbx - ltx, 0.f), ih = fmaxf(rby - lty, 0.f);
            const float inter = iw * ih;
            const float iou = inter / (parea + garea - inter + 1e-8f);

            const float ew = fmaxf(pax1, gax1) - fminf(pax0, gax0);
            const float eh = fmaxf(pay1, gay1) - fminf(pay0, gay0);
            const float cc2 = ew * ew + eh * eh + 1e-8f;
            const float dx = pxc - gxc, dy = pyc - gyc;
            const float diou = iou - (dx * dx + dy * dy) / cc2;

            const float cclass = lbuf[qrow * 80 + lab];
            const float cost = 5.f * l1 + 2.f * cclass + 2.f * diou
                             + (fgf[qrow] ? 0.f : 10000.f);

            out_cost[o] = cost;
            out_iou[o]  = iou;
            o += 2 * G_;
            s_cost[qls][g] = cost;

            // bottom-5 (cost, global q) lex insert: q's ascending per thread,
            // stable strict-< keeps smaller q ahead on ties
            { float x = cost; int qx = q;
              ins_level(c0, j0, x, qx);
              ins_level(c1, j1, x, qx);
              ins_level(c2, j2, x, qx);
              ins_level(c3, j3, x, qx);
              ins_level(c4, j4, x, qx); }
            // top-5 iou insert
            { float y = iou, m;
              m = fmaxf(t0, y); y = fminf(t0, y); t0 = m;
              m = fmaxf(t1, y); y = fminf(t1, y); t1 = m;
              m = fmaxf(t2, y); y = fminf(t2, y); t2 = m;
              m = fmaxf(t3, y); y = fminf(t3, y); t3 = m;
              t4 = fmaxf(t4, y); }
        }
        __syncthreads();   // s_cost complete

        // ---- row argmin (first-index tie-break), ALL 256 threads ----
        {
            const int part = tid & 15;     // 0..15
            const int row  = tid >> 4;     // 0..15
            float v = 1e38f; int mg = 0x7fffffff;
            #pragma unroll
            for (int j = 0; j < 8; ++j) {
                const int gg = part + 16 * j;          // ascending per lane
                const float c = s_cost[row][gg];
                if (c < v) { v = c; mg = gg; }         // strict <: first index
            }
            #pragma unroll
            for (int off = 1; off < 16; off <<= 1) {
                const float ov = __shfl_xor(v, off);
                const int   og = __shfl_xor(mg, off);
                if (ov < v || (ov == v && og < mg)) { v = ov; mg = og; }
            }
            if (part == 0) ramin[b * Q_ + q0 + row] = mg;
        }
        __syncthreads();   // s_cost reusable (or overlay writable)
    }

    // ---- merge q-parity halves (khalf/phalf overlay s_cost; last argmin
    //      is barrier-separated above), write per (b, ci, g) lists ----
    if (qh == 1) {
        khalf[g][0] = packkey(c0, j0); khalf[g][1] = packkey(c1, j1);
        khalf[g][2] = packkey(c2, j2); khalf[g][3] = packkey(c3, j3);
        khalf[g][4] = packkey(c4, j4);
        phalf[g][0] = t0; phalf[g][1] = t1; phalf[g][2] = t2;
        phalf[g][3] = t3; phalf[g][4] = t4;
    }
    __syncthreads();
    if (qh == 0) {
        u64 a0 = packkey(c0, j0), a1 = packkey(c1, j1), a2 = packkey(c2, j2),
            a3 = packkey(c3, j3), a4 = packkey(c4, j4);
        merge5_asc(a0, a1, a2, a3, a4,
                   khalf[g][0], khalf[g][1], khalf[g][2], khalf[g][3], khalf[g][4]);
        merge5_desc(t0, t1, t2, t3, t4,
                    phalf[g][0], phalf[g][1], phalf[g][2], phalf[g][3], phalf[g][4]);
        // coalesced layout: [B][NCH][G][5]
        const size_t pbase = (((size_t)b * NCH + ci) * G_ + g) * 5;
        piou[pbase + 0] = t0; piou[pbase + 1] = t1; piou[pbase + 2] = t2;
        piou[pbase + 3] = t3; piou[pbase + 4] = t4;
        pcost[pbase + 0] = a0; pcost[pbase + 1] = a1; pcost[pbase + 2] = a2;
        pcost[pbase + 3] = a3; pcost[pbase + 4] = a4;
    }
}

// ---------------------------------------------------------------------------
// Kernel B: per-column, ONE WAVE (64 threads = one thread per chunk-list):
// butterfly-merge 64 sorted 5-lists -> cand, dyn_k, scatter cnt/gsel.
// ---------------------------------------------------------------------------
__global__ __launch_bounds__(64) void dynk_scatter_kernel(
    const u64*   __restrict__ pcost,
    const float* __restrict__ piou,
    u64* __restrict__ cand,
    int* __restrict__ cnt,
    int* __restrict__ gsel)
{
    const int col = blockIdx.x;          // b*G + g
    const int b = col >> 7, g = col & 127;
    const int ln = threadIdx.x;          // = chunk index ci (0..63)

    // layout [B][NCH][G][5]
    const size_t base = (((size_t)b * NCH + ln) * G_ + g) * 5;

    u64 k0 = pcost[base + 0], k1 = pcost[base + 1], k2 = pcost[base + 2],
        k3 = pcost[base + 3], k4 = pcost[base + 4];
    float t0 = piou[base + 0], t1 = piou[base + 1], t2 = piou[base + 2],
          t3 = piou[base + 3], t4 = piou[base + 4];

    #pragma unroll
    for (int off = 1; off < 64; off <<= 1) {
        merge5_asc(k0, k1, k2, k3, k4,
                   __shfl_xor(k0, off), __shfl_xor(k1, off), __shfl_xor(k2, off),
                   __shfl_xor(k3, off), __shfl_xor(k4, off));
        merge5_desc(t0, t1, t2, t3, t4,
                    __shfl_xor(t0, off), __shfl_xor(t1, off), __shfl_xor(t2, off),
                    __shfl_xor(t3, off), __shfl_xor(t4, off));
    }

    if (ln == 0) {
        cand[(size_t)col * 5 + 0] = k0;
        cand[(size_t)col * 5 + 1] = k1;
        cand[(size_t)col * 5 + 2] = k2;
        cand[(size_t)col * 5 + 3] = k3;
        cand[(size_t)col * 5 + 4] = k4;

        const float s = t0 + t1 + t2 + t3 + t4;
        int dynk = (int)s;
        if (dynk < 1) dynk = 1;
        if (dynk > 5) dynk = 5;
        const u64 ks[5] = {k0, k1, k2, k3, k4};
        #pragma unroll
        for (int i = 0; i < 5; ++i) {
            if (i < dynk) {
                const int q = (int)(ks[i] & 0xffffffffu);
                atomicAdd(&cnt[b * Q_ + q], 1);
                gsel[b * Q_ + q] = g;   // only read when cnt==1
            }
        }
    }
}

// ---------------------------------------------------------------------------
// Kernel C: per-batch event-driven refinement loop (1024 threads) — the
// verified round-1 structure.
// ---------------------------------------------------------------------------
__global__ __launch_bounds__(1024) void loop_kernel(
    const float* __restrict__ cost,
    const int* __restrict__ cnt,
    const int* __restrict__ gsel,
    const int* __restrict__ ramin,
    const u64* __restrict__ cand,
    int* __restrict__ rmatch_final)
{
    const int b = blockIdx.x, tid = threadIdx.x;
    const int wv = tid >> 6, ln = tid & 63;

    __shared__ short rmatch[Q_];            // 8 KB
    __shared__ unsigned char s_ra[Q_];      // 4 KB
    __shared__ int newh[Q_];                // 16 KB
    __shared__ unsigned char newg[Q_];      // 4 KB
    __shared__ u64 scand[G_][5];            // 5 KB
    __shared__ int ptrs[G_], col_cnt[G_], unm_list[G_], prop[G_], fb_slot[G_], touched[G_];
    __shared__ int n_unm, n_fb, n_touch;

    for (int q = tid; q < Q_; q += 1024) {
        const int c  = cnt[b * Q_ + q];
        const int ra = ramin[b * Q_ + q];
        s_ra[q] = (unsigned char)ra;
        newh[q] = 0;
        rmatch[q] = (c == 0) ? (short)-1
                             : (c == 1 ? (short)gsel[b * Q_ + q] : (short)ra);
    }
    if (tid < G_) { col_cnt[tid] = 0; ptrs[tid] = 0; }
    if (tid < G_ * 5)
        scand[tid / 5][tid % 5] = cand[(size_t)b * G_ * 5 + tid];
    __syncthreads();
    for (int q = tid; q < Q_; q += 1024)
        if (rmatch[q] >= 0) atomicAdd(&col_cnt[rmatch[q]], 1);
    __syncthreads();

    const float* costb = cost + (size_t)b * Q_ * G_;

    for (int it = 0; it < G_; ++it) {
        if (tid == 0) { n_unm = 0; n_fb = 0; n_touch = 0; }
        __syncthreads();
        if (tid < G_ && col_cnt[tid] == 0)
            unm_list[atomicAdd(&n_unm, 1)] = tid;
        __syncthreads();
        const int nu = n_unm;
        if (nu == 0) break;

        // propose: first unmatched candidate, else mark for fallback scan
        if (tid < nu) {
            const int g = unm_list[tid];
            int p = ptrs[g];
            int q = -1;
            while (p < 5) {
                const int cq = (int)(scand[g][p] & 0xffffffffu);
                if (rmatch[cq] < 0) { q = cq; break; }
                ++p;
            }
            ptrs[g] = p;
            prop[tid] = q;
            if (q < 0) fb_slot[atomicAdd(&n_fb, 1)] = tid;
        }
        __syncthreads();

        // wave-parallel fallback (16 waves): bottom-5 unmatched + refill.
        const int nf = n_fb;
        for (int i = wv; i < nf; i += 16) {
            const int slot = fb_slot[i];
            const int g = unm_list[slot];
            const float* colp = costb + g;
            u64 k0 = U64MAX, k1 = U64MAX, k2 = U64MAX, k3 = U64MAX, k4 = U64MAX;
            for (int q = ln; q < Q_; q += 64) {
                if (rmatch[q] < 0) {
                    const float v = colp[(size_t)q * G_];
                    const u64 kk = packkey(v, q);
                    if (kk < k4) {
                        if (kk < k0)      { k4 = k3; k3 = k2; k2 = k1; k1 = k0; k0 = kk; }
                        else if (kk < k1) { k4 = k3; k3 = k2; k2 = k1; k1 = kk; }
                        else if (kk < k2) { k4 = k3; k3 = k2; k2 = kk; }
                        else if (kk < k3) { k4 = k3; k3 = kk; }
                        else              { k4 = kk; }
                    }
                }
            }
            #pragma unroll
            for (int off = 1; off < 64; off <<= 1) {
                merge5_asc(k0, k1, k2, k3, k4,
                           __shfl_xor(k0, off), __shfl_xor(k1, off), __shfl_xor(k2, off),
                           __shfl_xor(k3, off), __shfl_xor(k4, off));
            }
            if (ln == 0) {
                scand[g][0] = k0; scand[g][1] = k1; scand[g][2] = k2;
                scand[g][3] = k3; scand[g][4] = k4;
                ptrs[g] = 0;
                prop[slot] = (int)(k0 & 0xffffffffu);
            }
        }
        __syncthreads();

        // hits
        if (tid < nu) {
            const int q = prop[tid];
            newg[q] = (unsigned char)unm_list[tid];  // consumed only when nh==1
            if (atomicAdd(&newh[q], 1) == 0)
                touched[atomicAdd(&n_touch, 1)] = q;
        }
        __syncthreads();

        // resolve (dedup): hits only land on unmatched rows
        const int nt = n_touch;
        if (tid < nt) {
            const int q = touched[tid];
            const int nh = newh[q];
            const int gg = (nh == 1) ? (int)newg[q] : (int)s_ra[q];
            rmatch[q] = (short)gg;
            atomicAdd(&col_cnt[gg], 1);
            newh[q] = 0;
        }
        __syncthreads();
    }

    for (int q = tid; q < Q_; q += 1024)
        rmatch_final[b * Q_ + q] = rmatch[q];
}

// ---------------------------------------------------------------------------
// Kernel D: expand rmatch -> full match plane (fully parallel float4 writes).
// ---------------------------------------------------------------------------
__global__ __launch_bounds__(256) void expand_kernel(
    const int* __restrict__ rmatch_final, float* __restrict__ out_match)
{
    const int idx = blockIdx.x * 256 + threadIdx.x;  // float4 index
    const int row = idx >> 5;                        // G/4 = 32 float4 per row
    const int gb  = (idx & 31) << 2;
    const int rm  = rmatch_final[row];
    float4 o;
    o.x = (rm == gb)     ? 1.f : 0.f;
    o.y = (rm == gb + 1) ? 1.f : 0.f;
    o.z = (rm == gb + 2) ? 1.f : 0.f;
    o.w = (rm == gb + 3) ? 1.f : 0.f;
    ((float4*)out_match)[idx] = o;
}

extern "C" void kernel_launch(void* const* d_in, const int* in_sizes, int n_in,
                              void* d_out, int out_size, void* d_ws, size_t ws_size,
                              hipStream_t stream) {
    const float* logits  = (const float*)d_in[0];
    const float* pboxes  = (const float*)d_in[1];
    const float* gboxes  = (const float*)d_in[2];
    const int*   glabels = (const int*)d_in[3];

    float* out = (float*)d_out;
    const size_t BQG = (size_t)B_ * Q_ * G_;
    float* out_match = out;
    float* out_cost  = out + BQG;
    float* out_iou   = out + 2 * BQG;

    // workspace layout (~9 MB)
    char* ws = (char*)d_ws;
    size_t off = 0;
    u64*   pcost  = (u64*)  (ws + off); off += (size_t)B_ * NCH * G_ * 5 * 8;
    float* piou   = (float*)(ws + off); off += (size_t)B_ * NCH * G_ * 5 * 4;
    u64*   cand   = (u64*)  (ws + off); off += (size_t)B_ * G_ * 5 * 8;
    int*   ramin  = (int*)  (ws + off); off += (size_t)B_ * Q_ * 4;
    int*   cnt    = (int*)  (ws + off); off += (size_t)B_ * Q_ * 4;
    int*   gsel   = (int*)  (ws + off); off += (size_t)B_ * Q_ * 4;
    int*   rmf    = (int*)  (ws + off); off += (size_t)B_ * Q_ * 4;

    fused_cost_kernel<<<dim3(NCH, B_), 256, 0, stream>>>(
        logits, pboxes, gboxes, glabels, out_cost, out_iou, piou, pcost, ramin, cnt);
    dynk_scatter_kernel<<<B_ * G_, 64, 0, stream>>>(pcost, piou, cand, cnt, gsel);
    loop_kernel<<<B_, 1024, 0, stream>>>(out_cost, cnt, gsel, ramin, cand, rmf);
    expand_kernel<<<(int)(BQG / 4 / 256), 256, 0, stream>>>(rmf, out_match);
}